// Round 1
// baseline (4444.766 us; speedup 1.0000x reference)
//
#include <hip/hip_runtime.h>

#define NATOM 65536
#define MNBR 12
#define NMROW (NATOM*MNBR)      // 786432
#define ORIG 92
#define NBRF 41
#define AF 64
#define HF 128
#define NCRYS 1024
#define TSTR 200                // T-tile LDS row stride (bf16 elems): 400B, 16B-aligned, bank-optimal
#define TILE_ROWS 128
#define NTILES (NMROW/TILE_ROWS) // 6144
#define EPSBN 1e-5f

typedef __attribute__((ext_vector_type(8))) short short8;
typedef __attribute__((ext_vector_type(4))) float floatx4;

__device__ __forceinline__ float softplusf_(float x){ return fmaxf(x,0.f) + log1pf(expf(-fabsf(x))); }
__device__ __forceinline__ float sigmoidf_(float x){ return 1.f/(1.f+expf(-x)); }
__device__ __forceinline__ short f2bf(float x){
    unsigned u = __float_as_uint(x);
    u += 0x7fffu + ((u >> 16) & 1u);   // RNE
    return (short)(u >> 16);
}

// ---------------- embedding: afea = atom_fea @ emb_w + emb_b ----------------
__global__ void k_embed(const float* __restrict__ atom_fea, const float* __restrict__ emb_w,
                        const float* __restrict__ emb_b, float* __restrict__ afea,
                        float* __restrict__ ident, short* __restrict__ abf)
{
    __shared__ float wl[ORIG*AF];
    __shared__ float bl[AF];
    __shared__ float rows[4*ORIG];
    int tid = threadIdx.x;
    for (int i = tid; i < ORIG*AF; i += 256) wl[i] = emb_w[i];
    if (tid < AF) bl[tid] = emb_b[tid];
    __syncthreads();
    for (int t = blockIdx.x; t < NATOM/4; t += gridDim.x) {
        for (int i = tid; i < 4*ORIG; i += 256) rows[i] = atom_fea[t*4*ORIG + i];
        __syncthreads();
        int r = tid >> 6, c = tid & 63;
        float acc = bl[c];
        const float* rp = &rows[r*ORIG];
        #pragma unroll 4
        for (int k = 0; k < ORIG; ++k) acc += rp[k] * wl[k*AF + c];
        int n = t*4 + r;
        afea[n*AF + c] = acc;
        ident[n*AF + c] = acc;
        abf[n*AF + c] = f2bf(acc);
        __syncthreads();
    }
}

// ---------------- conv GEMM: gated = [self|nbr|edge] @ W + b ----------------
// PASS2=0: accumulate per-channel sum/sumsq of gated into stats1[0:128|128:256]
// PASS2=1: apply BN1 scale/shift, sigmoid(filt)*softplus(core), sum over m -> nsum
template<int PASS2>
__global__ __launch_bounds__(256, 2)
void k_conv(const short* __restrict__ abf, const float* __restrict__ nbr_fea,
            const int* __restrict__ nbr_idx, const float* __restrict__ W,
            const float* __restrict__ bias,
            float* __restrict__ stats1, const float* __restrict__ bn1ss,
            float* __restrict__ nsum)
{
    __shared__ __align__(16) char smem[TILE_ROWS*TSTR*2];   // 51200 B
    short* tl = (short*)smem;
    float* ep = (float*)smem;    // pass2 epilogue overlay: 2 x [64][66] floats

    int tid = threadIdx.x;
    int lane = tid & 63;
    int wave = tid >> 6;
    int l15 = lane & 15, q = lane >> 4;
    int rh = wave & 1;           // row half (0: rows 0-63, 1: rows 64-127)
    int chh = wave >> 1;         // channel half (0: filt ch0-63, 1: core ch64-127)
    int chbase = chh * 64;

    // W fragments in registers: B[k=q*8+j][n=l15] per (ks, ct)
    short8 wf[6][4];
    float bsv[4], sc[4], sh[4];
    for (int ct = 0; ct < 4; ++ct) {
        int c = chbase + ct*16 + l15;
        bsv[ct] = bias[c];
        if (PASS2) { sc[ct] = bn1ss[c]; sh[ct] = bn1ss[128 + c]; }
        for (int ks = 0; ks < 6; ++ks) {
            short8 v = {0,0,0,0,0,0,0,0};
            #pragma unroll
            for (int j = 0; j < 8; ++j) {
                int k = ks*32 + q*8 + j;
                if (k < 169) v[j] = f2bf(W[k*128 + c]);
            }
            wf[ks][ct] = v;
        }
    }

    float s_acc[4]  = {0.f,0.f,0.f,0.f};
    float s2_acc[4] = {0.f,0.f,0.f,0.f};

    for (int tile = blockIdx.x; tile < NTILES; tile += gridDim.x) {
        int R0 = tile * TILE_ROWS;
        __syncthreads();   // previous iteration's LDS use done
        // stage T tile: per row 24 chunks of 8 bf16 (self 0-7 | nbr 8-15 | edge 16-21 | zero 22-23)
        for (int i = tid; i < TILE_ROWS*24; i += 256) {
            int row = i / 24, chunk = i % 24;
            int R = R0 + row;
            short8 v = {0,0,0,0,0,0,0,0};
            if (chunk < 8) {
                int n = R / MNBR;
                v = *(const short8*)(abf + n*AF + chunk*8);
            } else if (chunk < 16) {
                int j = nbr_idx[R];
                v = *(const short8*)(abf + j*AF + (chunk-8)*8);
            } else if (chunk < 22) {
                int kb = (chunk-16)*8;
                const float* src = nbr_fea + (long)R*NBRF + kb;
                #pragma unroll
                for (int j = 0; j < 8; ++j) if (kb + j < NBRF) v[j] = f2bf(src[j]);
            }
            *(short8*)(tl + row*TSTR + chunk*8) = v;
        }
        __syncthreads();

        floatx4 acc[4][4];
        for (int rt=0; rt<4; ++rt) for (int ct=0; ct<4; ++ct)
            acc[rt][ct] = (floatx4){bsv[ct], bsv[ct], bsv[ct], bsv[ct]};

        #pragma unroll
        for (int ks = 0; ks < 6; ++ks) {
            short8 av[4];
            #pragma unroll
            for (int rt=0; rt<4; ++rt)
                av[rt] = *(const short8*)(tl + (rh*64 + rt*16 + l15)*TSTR + ks*32 + q*8);
            #pragma unroll
            for (int rt=0; rt<4; ++rt)
                #pragma unroll
                for (int ct=0; ct<4; ++ct)
                    acc[rt][ct] = __builtin_amdgcn_mfma_f32_16x16x32_bf16(av[rt], wf[ks][ct], acc[rt][ct], 0, 0, 0);
        }

        if (!PASS2) {
            for (int ct=0; ct<4; ++ct)
                for (int rt=0; rt<4; ++rt)
                    #pragma unroll
                    for (int r=0; r<4; ++r) {
                        float v = acc[rt][ct][r];
                        s_acc[ct] += v; s2_acc[ct] += v*v;
                    }
        } else {
            for (int phase = 0; phase < 2; ++phase) {
                __syncthreads();  // tl reads (k-loop) / previous phase reads complete
                if (rh == phase) {
                    for (int rt=0; rt<4; ++rt)
                        for (int ct=0; ct<4; ++ct)
                            #pragma unroll
                            for (int r=0; r<4; ++r) {
                                float g = acc[rt][ct][r] * sc[ct] + sh[ct];
                                int lrow = rt*16 + q*4 + r;          // row within half
                                int c16  = ct*16 + l15;              // channel within half
                                ep[chh*(64*66) + lrow*66 + c16] = chh ? softplusf_(g) : sigmoidf_(g);
                            }
                }
                __syncthreads();
                // combine + per-atom running sum over m
                int c = tid & 63, slot = tid >> 6;
                float run = 0.f; int cura = -1;
                for (int rr = slot*16; rr < slot*16 + 16; ++rr) {
                    float p = ep[rr*66 + c] * ep[64*66 + rr*66 + c];
                    int R = R0 + phase*64 + rr;
                    int a = R / MNBR;
                    if (a != cura) {
                        if (cura >= 0) atomicAdd(&nsum[cura*AF + c], run);
                        run = 0.f; cura = a;
                    }
                    run += p;
                }
                atomicAdd(&nsum[cura*AF + c], run);
            }
        }
    }

    if (!PASS2) {
        for (int ct=0; ct<4; ++ct) {
            float s = s_acc[ct], s2 = s2_acc[ct];
            s  += __shfl_xor(s, 16);  s  += __shfl_xor(s, 32);
            s2 += __shfl_xor(s2, 16); s2 += __shfl_xor(s2, 32);
            if (q == 0) {
                int c = chbase + ct*16 + l15;
                atomicAdd(&stats1[c], s);
                atomicAdd(&stats1[128 + c], s2);
            }
        }
    }
}

__global__ void k_bn1fin(const float* __restrict__ stats1, const float* __restrict__ g,
                         const float* __restrict__ b, float* __restrict__ bn1ss)
{
    int c = threadIdx.x;
    float mean = stats1[c] * (1.f/NMROW);
    float var  = stats1[128+c] * (1.f/NMROW) - mean*mean;
    float scale = g[c] * rsqrtf(var + EPSBN);
    bn1ss[c] = scale;
    bn1ss[128+c] = b[c] - mean*scale;
}

__global__ void k_bn2stats(const float* __restrict__ nsum, float* __restrict__ stats2)
{
    __shared__ float ls[256], ls2[256];
    int tid = threadIdx.x;
    int g = blockIdx.x*256 + tid;       // 1024 blocks x 256
    int c = g & 63;
    int chunk = g >> 6;                 // 4096 chunks x 16 rows
    float s=0.f, s2=0.f;
    for (int i = 0; i < 16; ++i) {
        float v = nsum[(chunk*16 + i)*64 + c];
        s += v; s2 += v*v;
    }
    ls[tid]=s; ls2[tid]=s2; __syncthreads();
    if (tid < 128){ ls[tid]+=ls[tid+128]; ls2[tid]+=ls2[tid+128]; } __syncthreads();
    if (tid < 64){
        atomicAdd(&stats2[tid],    ls[tid]+ls[tid+64]);
        atomicAdd(&stats2[64+tid], ls2[tid]+ls2[tid+64]);
    }
}

__global__ void k_update(float* __restrict__ afea, float* __restrict__ ident,
                         short* __restrict__ abf, const float* __restrict__ nsum,
                         const float* __restrict__ stats2,
                         const float* __restrict__ g2, const float* __restrict__ b2)
{
    int g = blockIdx.x*256 + threadIdx.x;   // 16384 blocks
    int c = g & 63;
    float mean = stats2[c] * (1.f/NATOM);
    float var  = stats2[64+c] * (1.f/NATOM) - mean*mean;
    float scale = g2[c]*rsqrtf(var + EPSBN);
    float shift = b2[c] - mean*scale;
    float ns = nsum[g]*scale + shift;
    float v = softplusf_(afea[g] + ns) + ident[g];
    afea[g] = v; ident[g] = v; abf[g] = f2bf(v);
}

__global__ void k_pool(const float* __restrict__ afea, const int* __restrict__ cidx,
                       float* __restrict__ pool, float* __restrict__ cnt)
{
    int g = blockIdx.x*256 + threadIdx.x;   // 1024 blocks
    int c = g & 63; int chunk = g >> 6;     // 4096 chunks x 16 atoms
    float run = 0.f, rc = 0.f; int cur = -1;
    for (int i = 0; i < 16; ++i) {
        int a = chunk*16 + i;
        int cr = cidx[a];
        float v = afea[a*64 + c];
        if (cr != cur) {
            if (cur >= 0) { atomicAdd(&pool[cur*64+c], run); if (c==0) atomicAdd(&cnt[cur], rc); }
            run = 0.f; rc = 0.f; cur = cr;
        }
        run += v; rc += 1.f;
    }
    atomicAdd(&pool[cur*64+c], run); if (c==0) atomicAdd(&cnt[cur], rc);
}

__global__ void k_head(const float* __restrict__ pool, const float* __restrict__ cnt,
                       const float* __restrict__ fc1w, const float* __restrict__ fc1b,
                       const float* __restrict__ o1w, const float* __restrict__ o1b,
                       const float* __restrict__ o2w, const float* __restrict__ o2b,
                       float* __restrict__ dout)
{
    __shared__ float spv[64], crys[128], h1[64];
    int b = blockIdx.x, tid = threadIdx.x;
    if (tid < 64) {
        float ct = fmaxf(cnt[b], 1.f);
        spv[tid] = softplusf_(pool[b*64+tid] / ct);
    }
    __syncthreads();
    float a = fc1b[tid];
    for (int k = 0; k < 64; ++k) a += spv[k] * fc1w[k*128 + tid];
    float v = softplusf_(a);
    crys[tid] = v;
    dout[NCRYS + b*128 + tid] = v;
    __syncthreads();
    if (tid < 64) {
        float a2 = o1b[tid];
        for (int k = 0; k < 128; ++k) a2 += crys[k] * o1w[k*64 + tid];
        h1[tid] = softplusf_(a2) * o2w[tid];
    }
    __syncthreads();
    if (tid == 0) {
        float s = o2b[0];
        for (int j = 0; j < 64; ++j) s += h1[j];
        dout[b] = s;
    }
}

extern "C" void kernel_launch(void* const* d_in, const int* in_sizes, int n_in,
                              void* d_out, int out_size, void* d_ws, size_t ws_size,
                              hipStream_t stream)
{
    const float* atom_fea = (const float*)d_in[0];
    const float* nbr_fea  = (const float*)d_in[1];
    const int*   nbr_idx  = (const int*)d_in[2];
    const int*   cidx     = (const int*)d_in[3];
    const float* emb_w    = (const float*)d_in[4];
    const float* emb_b    = (const float*)d_in[5];
    const float* cfw      = (const float*)d_in[6];
    const float* cfb      = (const float*)d_in[7];
    const float* bn1g     = (const float*)d_in[8];
    const float* bn1b     = (const float*)d_in[9];
    const float* bn2g     = (const float*)d_in[10];
    const float* bn2b     = (const float*)d_in[11];
    const float* fc1w     = (const float*)d_in[12];
    const float* fc1b     = (const float*)d_in[13];
    const float* o1w      = (const float*)d_in[14];
    const float* o1b      = (const float*)d_in[15];
    const float* o2w      = (const float*)d_in[16];
    const float* o2b      = (const float*)d_in[17];

    float* ws    = (float*)d_ws;
    float* afea  = ws;                     // N*64
    float* ident = ws + 4194304;           // N*64
    float* nsum  = ws + 8388608;           // N*64
    short* abf   = (short*)(ws + 12582912);// N*64 bf16
    float* stats = ws + 14680064;          // 3 layers x 640 (sum128|sumsq128|scale128|shift128|s2_64|sq2_64)
    float* pool  = ws + 14681984;          // 1024*64
    float* cnt   = ws + 14747520;          // 1024

    hipMemsetAsync(stats, 0, (1920 + 65536 + 1024)*sizeof(float), stream);

    k_embed<<<2048, 256, 0, stream>>>(atom_fea, emb_w, emb_b, afea, ident, abf);

    for (int L = 0; L < 3; ++L) {
        float* st1 = stats + L*640;
        float* ss  = st1 + 256;
        float* st2 = st1 + 512;
        const float* W  = cfw + L*169*128;
        const float* bs = cfb + L*128;
        hipMemsetAsync(nsum, 0, 4194304*sizeof(float), stream);
        k_conv<0><<<1536, 256, 0, stream>>>(abf, nbr_fea, nbr_idx, W, bs, st1, nullptr, nullptr);
        k_bn1fin<<<1, 128, 0, stream>>>(st1, bn1g + L*128, bn1b + L*128, ss);
        k_conv<1><<<1536, 256, 0, stream>>>(abf, nbr_fea, nbr_idx, W, bs, nullptr, ss, nsum);
        k_bn2stats<<<1024, 256, 0, stream>>>(nsum, st2);
        k_update<<<16384, 256, 0, stream>>>(afea, ident, abf, nsum, st2, bn2g + L*64, bn2b + L*64);
    }
    k_pool<<<1024, 256, 0, stream>>>(afea, cidx, pool, cnt);
    k_head<<<NCRYS, 128, 0, stream>>>(pool, cnt, fc1w, fc1b, o1w, o1b, o2w, o2b, (float*)d_out);
}

// Round 2
// 1431.380 us; speedup vs baseline: 3.1052x; 3.1052x over previous
//
#include <hip/hip_runtime.h>

#define NATOM 65536
#define MNBR 12
#define NMROW (NATOM*MNBR)      // 786432
#define ORIG 92
#define NBRF 41
#define AF 64
#define HF 128
#define NCRYS 1024
#define TILE_ROWS 96            // 8 atoms exactly
#define NTILES (NMROW/TILE_ROWS) // 8192
#define EPSBN 1e-5f
#define NBP 48                  // padded edge width (bf16)

typedef __attribute__((ext_vector_type(8))) short short8;
typedef __attribute__((ext_vector_type(4))) float floatx4;

__device__ __forceinline__ float softplusf_(float x){ return fmaxf(x,0.f) + log1pf(expf(-fabsf(x))); }
__device__ __forceinline__ float sigmoidf_(float x){ return 1.f/(1.f+expf(-x)); }
__device__ __forceinline__ short f2bf(float x){
    unsigned u = __float_as_uint(x);
    u += 0x7fffu + ((u >> 16) & 1u);   // RNE
    return (short)(u >> 16);
}

// ---------------- embedding: afea = atom_fea @ emb_w + emb_b ----------------
__global__ void k_embed(const float* __restrict__ atom_fea, const float* __restrict__ emb_w,
                        const float* __restrict__ emb_b, float* __restrict__ afea,
                        short* __restrict__ abf)
{
    __shared__ float wl[ORIG*AF];
    __shared__ float bl[AF];
    __shared__ float rows[4*ORIG];
    int tid = threadIdx.x;
    for (int i = tid; i < ORIG*AF; i += 256) wl[i] = emb_w[i];
    if (tid < AF) bl[tid] = emb_b[tid];
    __syncthreads();
    for (int t = blockIdx.x; t < NATOM/4; t += gridDim.x) {
        for (int i = tid; i < 4*ORIG; i += 256) rows[i] = atom_fea[t*4*ORIG + i];
        __syncthreads();
        int r = tid >> 6, c = tid & 63;
        float acc = bl[c];
        const float* rp = &rows[r*ORIG];
        #pragma unroll 4
        for (int k = 0; k < ORIG; ++k) acc += rp[k] * wl[k*AF + c];
        int n = t*4 + r;
        afea[n*AF + c] = acc;
        abf[n*AF + c] = f2bf(acc);
        __syncthreads();
    }
}

// ------------- one-time: nbr_fea fp32 [NM][41] -> bf16 padded [NM][48] -------------
__global__ void k_prep_nbr(const float* __restrict__ nbr_fea, short* __restrict__ nbf)
{
    int g = blockIdx.x*256 + threadIdx.x;   // NMROW*NBP threads
    int row = g / NBP, k = g % NBP;
    float v = (k < NBRF) ? nbr_fea[row*NBRF + k] : 0.f;
    nbf[g] = f2bf(v);
}

// ------------- per-layer: W fp32 [169][128] -> bf16 transposed padded [128][192] -------------
__global__ void k_prep_w(const float* __restrict__ W, short* __restrict__ wt)
{
    int g = blockIdx.x*256 + threadIdx.x;   // 128*192 threads
    int c = g / 192, k = g % 192;
    wt[g] = (k < 169) ? f2bf(W[k*128 + c]) : (short)0;
}

// ---------------- conv GEMM: gated = [self|nbr|edge] @ W + b ----------------
// Tile = 96 rows (8 atoms) x 128 ch. Wave (rh,chh): rows rh*48..+48,
// channels: ct 0,1 -> filt chh*32+ct*16 ; ct 2,3 -> core 64+chh*32+(ct-2)*16.
// PASS2=0: per-channel sum/sumsq of gated -> stats1. PASS2=1: BN1 + sig*sp, m-sum -> nsum.
template<int PASS2>
__global__ __launch_bounds__(256, 2)
void k_conv(const short* __restrict__ abf, const short* __restrict__ nbf,
            const int* __restrict__ nbr_idx, const short* __restrict__ wt,
            const float* __restrict__ bias,
            float* __restrict__ stats1, const float* __restrict__ bn1ss,
            float* __restrict__ nsum)
{
    __shared__ float pbuf[4][48*33];   // wave-private transpose buffers (pass2)

    int tid = threadIdx.x;
    int lane = tid & 63;
    int wave = tid >> 6;
    int l15 = lane & 15, q = lane >> 4;
    int rh = wave & 1;            // row half: rows rh*48 .. rh*48+47
    int chh = wave >> 1;          // channel sub-half

    int cch[4];
    #pragma unroll
    for (int ct = 0; ct < 4; ++ct)
        cch[ct] = (ct < 2) ? (chh*32 + ct*16 + l15) : (64 + chh*32 + (ct-2)*16 + l15);

    short8 wf[6][4];
    float bsv[4], sc[4], sh[4];
    #pragma unroll
    for (int ct = 0; ct < 4; ++ct) {
        int c = cch[ct];
        bsv[ct] = bias[c];
        if (PASS2) { sc[ct] = bn1ss[c]; sh[ct] = bn1ss[128 + c]; }
        #pragma unroll
        for (int ks = 0; ks < 6; ++ks)
            wf[ks][ct] = *(const short8*)(wt + c*192 + ks*32 + q*8);
    }

    float s_acc[4]  = {0.f,0.f,0.f,0.f};
    float s2_acc[4] = {0.f,0.f,0.f,0.f};
    const short8 zf = {0,0,0,0,0,0,0,0};

    for (int tile = blockIdx.x; tile < NTILES; tile += gridDim.x) {
        int Rb = tile*TILE_ROWS + rh*48;

        short8 av[3][6];
        int Rr[3], nj[3];
        #pragma unroll
        for (int rt = 0; rt < 3; ++rt) Rr[rt] = Rb + rt*16 + l15;
        #pragma unroll
        for (int rt = 0; rt < 3; ++rt) nj[rt] = nbr_idx[Rr[rt]];
        #pragma unroll
        for (int rt = 0; rt < 3; ++rt) {
            unsigned n = (unsigned)Rr[rt] / 12u;
            const short* sp0 = abf + n*64 + q*8;
            av[rt][0] = *(const short8*)(sp0);
            av[rt][1] = *(const short8*)(sp0 + 32);
            const short* np0 = abf + nj[rt]*64 + q*8;
            av[rt][2] = *(const short8*)(np0);
            av[rt][3] = *(const short8*)(np0 + 32);
            const short* ep = nbf + (long)Rr[rt]*NBP;
            av[rt][4] = *(const short8*)(ep + q*8);
            av[rt][5] = (q < 2) ? *(const short8*)(ep + 32 + q*8) : zf;
        }

        floatx4 acc[3][4];
        #pragma unroll
        for (int rt=0; rt<3; ++rt)
            #pragma unroll
            for (int ct=0; ct<4; ++ct)
                acc[rt][ct] = (floatx4){bsv[ct], bsv[ct], bsv[ct], bsv[ct]};

        #pragma unroll
        for (int ks = 0; ks < 6; ++ks)
            #pragma unroll
            for (int rt = 0; rt < 3; ++rt)
                #pragma unroll
                for (int ct = 0; ct < 4; ++ct)
                    acc[rt][ct] = __builtin_amdgcn_mfma_f32_16x16x32_bf16(av[rt][ks], wf[ks][ct], acc[rt][ct], 0, 0, 0);

        if (!PASS2) {
            #pragma unroll
            for (int ct=0; ct<4; ++ct)
                #pragma unroll
                for (int rt=0; rt<3; ++rt)
                    #pragma unroll
                    for (int r=0; r<4; ++r) {
                        float v = acc[rt][ct][r];
                        s_acc[ct] += v; s2_acc[ct] += v*v;
                    }
        } else {
            // p = sigmoid(BN(filt)) * softplus(BN(core)); lane-local pairing (ct, ct+2)
            float* pb = pbuf[wave];
            #pragma unroll
            for (int rt=0; rt<3; ++rt)
                #pragma unroll
                for (int ct=0; ct<2; ++ct)
                    #pragma unroll
                    for (int r=0; r<4; ++r) {
                        float f = acc[rt][ct][r]   * sc[ct]   + sh[ct];
                        float g = acc[rt][ct+2][r] * sc[ct+2] + sh[ct+2];
                        float p = sigmoidf_(f) * softplusf_(g);
                        int row = rt*16 + q*4 + r;
                        pb[row*33 + ct*16 + l15] = p;
                    }
            __syncthreads();
            // m-sum: wave's 48 rows = 4 atoms, 32 channels; direct stores (tile owns atoms)
            {
                int c = lane & 31, sub = lane >> 5;
                #pragma unroll
                for (int a = 0; a < 2; ++a) {
                    int atom = sub*2 + a;
                    float s = 0.f;
                    #pragma unroll
                    for (int i = 0; i < 12; ++i) s += pb[(atom*12 + i)*33 + c];
                    nsum[(tile*8 + rh*4 + atom)*AF + chh*32 + c] = s;
                }
            }
            __syncthreads();
        }
    }

    if (!PASS2) {
        #pragma unroll
        for (int ct=0; ct<4; ++ct) {
            float s = s_acc[ct], s2 = s2_acc[ct];
            s  += __shfl_xor(s, 16);  s  += __shfl_xor(s, 32);
            s2 += __shfl_xor(s2, 16); s2 += __shfl_xor(s2, 32);
            if (q == 0) {
                atomicAdd(&stats1[cch[ct]], s);
                atomicAdd(&stats1[128 + cch[ct]], s2);
            }
        }
    }
}

__global__ void k_bn1fin(const float* __restrict__ stats1, const float* __restrict__ g,
                         const float* __restrict__ b, float* __restrict__ bn1ss)
{
    int c = threadIdx.x;
    float mean = stats1[c] * (1.f/NMROW);
    float var  = stats1[128+c] * (1.f/NMROW) - mean*mean;
    float scale = g[c] * rsqrtf(var + EPSBN);
    bn1ss[c] = scale;
    bn1ss[128+c] = b[c] - mean*scale;
}

__global__ void k_bn2stats(const float* __restrict__ nsum, float* __restrict__ stats2)
{
    __shared__ float ls[256], ls2[256];
    int tid = threadIdx.x;
    int g = blockIdx.x*256 + tid;       // 1024 blocks x 256
    int c = g & 63;
    int chunk = g >> 6;                 // 4096 chunks x 16 rows
    float s=0.f, s2=0.f;
    for (int i = 0; i < 16; ++i) {
        float v = nsum[(chunk*16 + i)*64 + c];
        s += v; s2 += v*v;
    }
    ls[tid]=s; ls2[tid]=s2; __syncthreads();
    if (tid < 128){ ls[tid]+=ls[tid+128]; ls2[tid]+=ls2[tid+128]; } __syncthreads();
    if (tid < 64){
        atomicAdd(&stats2[tid],    ls[tid]+ls[tid+64]);
        atomicAdd(&stats2[64+tid], ls2[tid]+ls2[tid+64]);
    }
}

__global__ void k_update(float* __restrict__ afea, short* __restrict__ abf,
                         const float* __restrict__ nsum,
                         const float* __restrict__ stats2,
                         const float* __restrict__ g2, const float* __restrict__ b2)
{
    int g = blockIdx.x*256 + threadIdx.x;   // 16384 blocks
    int c = g & 63;
    float mean = stats2[c] * (1.f/NATOM);
    float var  = stats2[64+c] * (1.f/NATOM) - mean*mean;
    float scale = g2[c]*rsqrtf(var + EPSBN);
    float shift = b2[c] - mean*scale;
    float ns = nsum[g]*scale + shift;
    float a = afea[g];
    float v = softplusf_(a + ns) + a;       // afea == identity invariant
    afea[g] = v; abf[g] = f2bf(v);
}

__global__ void k_pool(const float* __restrict__ afea, const int* __restrict__ cidx,
                       float* __restrict__ pool, float* __restrict__ cnt)
{
    int g = blockIdx.x*256 + threadIdx.x;   // 1024 blocks
    int c = g & 63; int chunk = g >> 6;     // 4096 chunks x 16 atoms
    float run = 0.f, rc = 0.f; int cur = -1;
    for (int i = 0; i < 16; ++i) {
        int a = chunk*16 + i;
        int cr = cidx[a];
        float v = afea[a*64 + c];
        if (cr != cur) {
            if (cur >= 0) { atomicAdd(&pool[cur*64+c], run); if (c==0) atomicAdd(&cnt[cur], rc); }
            run = 0.f; rc = 0.f; cur = cr;
        }
        run += v; rc += 1.f;
    }
    atomicAdd(&pool[cur*64+c], run); if (c==0) atomicAdd(&cnt[cur], rc);
}

__global__ void k_head(const float* __restrict__ pool, const float* __restrict__ cnt,
                       const float* __restrict__ fc1w, const float* __restrict__ fc1b,
                       const float* __restrict__ o1w, const float* __restrict__ o1b,
                       const float* __restrict__ o2w, const float* __restrict__ o2b,
                       float* __restrict__ dout)
{
    __shared__ float spv[64], crys[128], h1[64];
    int b = blockIdx.x, tid = threadIdx.x;
    if (tid < 64) {
        float ct = fmaxf(cnt[b], 1.f);
        spv[tid] = softplusf_(pool[b*64+tid] / ct);
    }
    __syncthreads();
    float a = fc1b[tid];
    for (int k = 0; k < 64; ++k) a += spv[k] * fc1w[k*128 + tid];
    float v = softplusf_(a);
    crys[tid] = v;
    dout[NCRYS + b*128 + tid] = v;
    __syncthreads();
    if (tid < 64) {
        float a2 = o1b[tid];
        for (int k = 0; k < 128; ++k) a2 += crys[k] * o1w[k*64 + tid];
        h1[tid] = softplusf_(a2) * o2w[tid];
    }
    __syncthreads();
    if (tid == 0) {
        float s = o2b[0];
        for (int j = 0; j < 64; ++j) s += h1[j];
        dout[b] = s;
    }
}

extern "C" void kernel_launch(void* const* d_in, const int* in_sizes, int n_in,
                              void* d_out, int out_size, void* d_ws, size_t ws_size,
                              hipStream_t stream)
{
    const float* atom_fea = (const float*)d_in[0];
    const float* nbr_fea  = (const float*)d_in[1];
    const int*   nbr_idx  = (const int*)d_in[2];
    const int*   cidx     = (const int*)d_in[3];
    const float* emb_w    = (const float*)d_in[4];
    const float* emb_b    = (const float*)d_in[5];
    const float* cfw      = (const float*)d_in[6];
    const float* cfb      = (const float*)d_in[7];
    const float* bn1g     = (const float*)d_in[8];
    const float* bn1b     = (const float*)d_in[9];
    const float* bn2g     = (const float*)d_in[10];
    const float* bn2b     = (const float*)d_in[11];
    const float* fc1w     = (const float*)d_in[12];
    const float* fc1b     = (const float*)d_in[13];
    const float* o1w      = (const float*)d_in[14];
    const float* o1b      = (const float*)d_in[15];
    const float* o2w      = (const float*)d_in[16];
    const float* o2b      = (const float*)d_in[17];

    float* ws    = (float*)d_ws;
    float* afea  = ws;                         // [0, 4194304)
    float* nsum  = ws + 4194304;               // [4194304, 8388608)
    short* abf   = (short*)(ws + 8388608);     // 4194304 bf16 -> 2097152 floats
    short* nbf   = (short*)(ws + 10485760);    // NMROW*48 bf16 -> 18874368 floats
    short* wt    = (short*)(ws + 29360128);    // 128*192 bf16 -> 12288 floats
    float* stats = ws + 29372416;              // 3 layers x 640
    float* pool  = ws + 29374336;              // 1024*64
    float* cnt   = ws + 29439872;              // 1024

    hipMemsetAsync(stats, 0, (1920 + 65536 + 1024)*sizeof(float), stream);

    k_prep_nbr<<<(NMROW*NBP)/256, 256, 0, stream>>>(nbr_fea, nbf);
    k_embed<<<2048, 256, 0, stream>>>(atom_fea, emb_w, emb_b, afea, abf);

    for (int L = 0; L < 3; ++L) {
        float* st1 = stats + L*640;
        float* ss  = st1 + 256;
        float* st2 = st1 + 512;
        k_prep_w<<<(128*192)/256, 256, 0, stream>>>(cfw + L*169*128, wt);
        k_conv<0><<<2048, 256, 0, stream>>>(abf, nbf, nbr_idx, wt, cfb + L*128, st1, nullptr, nullptr);
        k_bn1fin<<<1, 128, 0, stream>>>(st1, bn1g + L*128, bn1b + L*128, ss);
        k_conv<1><<<2048, 256, 0, stream>>>(abf, nbf, nbr_idx, wt, cfb + L*128, nullptr, ss, nsum);
        k_bn2stats<<<1024, 256, 0, stream>>>(nsum, st2);
        k_update<<<16384, 256, 0, stream>>>(afea, abf, nsum, st2, bn2g + L*64, bn2b + L*64);
    }
    k_pool<<<1024, 256, 0, stream>>>(afea, cidx, pool, cnt);
    k_head<<<NCRYS, 128, 0, stream>>>(pool, cnt, fc1w, fc1b, o1w, o1b, o2w, o2b, (float*)d_out);
}

// Round 3
// 1387.278 us; speedup vs baseline: 3.2039x; 1.0318x over previous
//
#include <hip/hip_runtime.h>

#define NATOM 65536
#define MNBR 12
#define NMROW (NATOM*MNBR)      // 786432
#define ORIG 92
#define NBRF 41
#define AF 64
#define HF 128
#define NCRYS 1024
#define TILE_ROWS 96            // 8 atoms exactly
#define NTILES (NMROW/TILE_ROWS) // 8192
#define EPSBN 1e-5f
#define NBP 48                  // padded edge width (bf16)

typedef __attribute__((ext_vector_type(8))) short short8;
typedef __attribute__((ext_vector_type(4))) float floatx4;

__device__ __forceinline__ float softplusf_(float x){ return fmaxf(x,0.f) + log1pf(expf(-fabsf(x))); }
__device__ __forceinline__ float sigmoidf_(float x){ return 1.f/(1.f+expf(-x)); }
__device__ __forceinline__ short f2bf(float x){
    unsigned u = __float_as_uint(x);
    u += 0x7fffu + ((u >> 16) & 1u);   // RNE
    return (short)(u >> 16);
}

// ---------------- embedding: afea = atom_fea @ emb_w + emb_b ----------------
__global__ void k_embed(const float* __restrict__ atom_fea, const float* __restrict__ emb_w,
                        const float* __restrict__ emb_b, float* __restrict__ afea,
                        short* __restrict__ abf)
{
    __shared__ float wl[ORIG*AF];
    __shared__ float bl[AF];
    __shared__ float rows[4*ORIG];
    int tid = threadIdx.x;
    for (int i = tid; i < ORIG*AF; i += 256) wl[i] = emb_w[i];
    if (tid < AF) bl[tid] = emb_b[tid];
    __syncthreads();
    for (int t = blockIdx.x; t < NATOM/4; t += gridDim.x) {
        for (int i = tid; i < 4*ORIG; i += 256) rows[i] = atom_fea[t*4*ORIG + i];
        __syncthreads();
        int r = tid >> 6, c = tid & 63;
        float acc = bl[c];
        const float* rp = &rows[r*ORIG];
        #pragma unroll 4
        for (int k = 0; k < ORIG; ++k) acc += rp[k] * wl[k*AF + c];
        int n = t*4 + r;
        afea[n*AF + c] = acc;
        abf[n*AF + c] = f2bf(acc);
        __syncthreads();
    }
}

// ------------- one-time: nbr_fea fp32 [NM][41] -> bf16 padded [NM][48] -------------
__global__ void k_prep_nbr(const float* __restrict__ nbr_fea, short* __restrict__ nbf)
{
    int g = blockIdx.x*256 + threadIdx.x;   // NMROW*NBP threads
    int row = g / NBP, k = g % NBP;
    float v = (k < NBRF) ? nbr_fea[row*NBRF + k] : 0.f;
    nbf[g] = f2bf(v);
}

// ------------- per-layer: W fp32 [169][128] -> bf16 fragments in LDS order -------------
// wt2 layout: [ks][q][c][j]  (6 x 4 x 128 x 8 shorts)  value = W[ks*32+q*8+j][c]
__global__ void k_prep_w(const float* __restrict__ W, short* __restrict__ wt2)
{
    int g = blockIdx.x*256 + threadIdx.x;   // 24576 threads
    int j = g & 7, c = (g >> 3) & 127, q = (g >> 10) & 3, ks = g >> 12;
    int k = ks*32 + q*8 + j;
    wt2[g] = (k < 169) ? f2bf(W[k*128 + c]) : (short)0;
}

// ---------------- conv GEMM: gated = [self|nbr|edge] @ W + b ----------------
// Tile = 96 rows (8 atoms) x 128 ch. Wave (rh,chh): rows rh*48..+48,
// channels: ct 0,1 -> filt chh*32+ct*16 ; ct 2,3 -> core 64+chh*32+(ct-2)*16.
// W fragments in LDS (block-shared); A fragments streamed per-ks from global.
// PASS2=0: per-channel sum/sumsq of gated -> stats1. PASS2=1: BN1 + sig*sp, m-sum -> nsum.
template<int PASS2>
__global__ __launch_bounds__(256, 2)
void k_conv(const short* __restrict__ abf, const short* __restrict__ nbf,
            const int* __restrict__ nbr_idx, const short* __restrict__ wt2,
            const float* __restrict__ bias,
            float* __restrict__ stats1, const float* __restrict__ bn1ss,
            float* __restrict__ nsum)
{
    __shared__ __align__(16) short wlds[24576];              // 49152 B
    __shared__ float pbuf[PASS2 ? 4*48*33 : 4];              // pass2: 25344 B

    int tid = threadIdx.x;
    int lane = tid & 63;
    int wave = tid >> 6;
    int l15 = lane & 15, q = lane >> 4;
    int rh = wave & 1;            // row half: rows rh*48 .. rh*48+47
    int chh = wave >> 1;          // channel sub-half

    // block prologue: stage W fragments into LDS (flat coalesced copy)
    {
        const short8* wg = (const short8*)wt2;
        short8* wl = (short8*)wlds;
        #pragma unroll
        for (int i = 0; i < 12; ++i) wl[i*256 + tid] = wg[i*256 + tid];
    }
    __syncthreads();

    int cch[4];
    #pragma unroll
    for (int ct = 0; ct < 4; ++ct)
        cch[ct] = (ct < 2) ? (chh*32 + ct*16 + l15) : (64 + chh*32 + (ct-2)*16 + l15);

    int woff[4];                  // LDS short-offset for (q, c); + ks*4096 inside loop
    #pragma unroll
    for (int ct = 0; ct < 4; ++ct) woff[ct] = q*1024 + cch[ct]*8;

    float bsv[4], sc[4], sh[4];
    #pragma unroll
    for (int ct = 0; ct < 4; ++ct) {
        bsv[ct] = bias[cch[ct]];
        if (PASS2) { sc[ct] = bn1ss[cch[ct]]; sh[ct] = bn1ss[128 + cch[ct]]; }
    }

    float s_acc[4]  = {0.f,0.f,0.f,0.f};
    float s2_acc[4] = {0.f,0.f,0.f,0.f};
    const short8 zf = {0,0,0,0,0,0,0,0};

    for (int tile = blockIdx.x; tile < NTILES; tile += gridDim.x) {
        int Rb = tile*TILE_ROWS + rh*48;

        const short* prow[3][3];  // [rt][0=self,1=nbr,2=edge]
        #pragma unroll
        for (int rt = 0; rt < 3; ++rt) {
            int R = Rb + rt*16 + l15;
            unsigned n = (unsigned)R / 12u;
            prow[rt][0] = abf + n*64 + q*8;
            prow[rt][1] = abf + (unsigned)nbr_idx[R]*64 + q*8;
            prow[rt][2] = nbf + (long)R*NBP + q*8;
        }

        floatx4 acc[3][4];
        #pragma unroll
        for (int rt=0; rt<3; ++rt)
            #pragma unroll
            for (int ct=0; ct<4; ++ct)
                acc[rt][ct] = (floatx4){bsv[ct], bsv[ct], bsv[ct], bsv[ct]};

        #pragma unroll
        for (int ks = 0; ks < 6; ++ks) {
            int sel = ks >> 1, off = (ks & 1) * 32;
            short8 av[3];
            #pragma unroll
            for (int rt = 0; rt < 3; ++rt) {
                if (ks == 5) av[rt] = (q < 2) ? *(const short8*)(prow[rt][2] + 32 + q*8) : zf;
                else         av[rt] = *(const short8*)(prow[rt][sel] + off);
            }
            short8 wv[4];
            #pragma unroll
            for (int ct = 0; ct < 4; ++ct)
                wv[ct] = *(const short8*)(wlds + ks*4096 + woff[ct]);
            #pragma unroll
            for (int rt = 0; rt < 3; ++rt)
                #pragma unroll
                for (int ct = 0; ct < 4; ++ct)
                    acc[rt][ct] = __builtin_amdgcn_mfma_f32_16x16x32_bf16(av[rt], wv[ct], acc[rt][ct], 0, 0, 0);
        }

        if (!PASS2) {
            #pragma unroll
            for (int ct=0; ct<4; ++ct)
                #pragma unroll
                for (int rt=0; rt<3; ++rt)
                    #pragma unroll
                    for (int r=0; r<4; ++r) {
                        float v = acc[rt][ct][r];
                        s_acc[ct] += v; s2_acc[ct] += v*v;
                    }
        } else {
            // p = sigmoid(BN(filt)) * softplus(BN(core)); lane-local pairing (ct, ct+2)
            float* pb = pbuf + wave*(48*33);
            #pragma unroll
            for (int rt=0; rt<3; ++rt)
                #pragma unroll
                for (int ct=0; ct<2; ++ct)
                    #pragma unroll
                    for (int r=0; r<4; ++r) {
                        float f = acc[rt][ct][r]   * sc[ct]   + sh[ct];
                        float g = acc[rt][ct+2][r] * sc[ct+2] + sh[ct+2];
                        float p = sigmoidf_(f) * softplusf_(g);
                        int row = rt*16 + q*4 + r;
                        pb[row*33 + ct*16 + l15] = p;
                    }
            __syncthreads();
            // m-sum: wave's 48 rows = 4 atoms, 32 channels; direct stores (tile owns atoms)
            {
                int c = lane & 31, sub = lane >> 5;
                #pragma unroll
                for (int a = 0; a < 2; ++a) {
                    int atom = sub*2 + a;
                    float s = 0.f;
                    #pragma unroll
                    for (int i = 0; i < 12; ++i) s += pb[(atom*12 + i)*33 + c];
                    nsum[(tile*8 + rh*4 + atom)*AF + chh*32 + c] = s;
                }
            }
            __syncthreads();
        }
    }

    if (!PASS2) {
        #pragma unroll
        for (int ct=0; ct<4; ++ct) {
            float s = s_acc[ct], s2 = s2_acc[ct];
            s  += __shfl_xor(s, 16);  s  += __shfl_xor(s, 32);
            s2 += __shfl_xor(s2, 16); s2 += __shfl_xor(s2, 32);
            if (q == 0) {
                atomicAdd(&stats1[cch[ct]], s);
                atomicAdd(&stats1[128 + cch[ct]], s2);
            }
        }
    }
}

__global__ void k_bn1fin(const float* __restrict__ stats1, const float* __restrict__ g,
                         const float* __restrict__ b, float* __restrict__ bn1ss)
{
    int c = threadIdx.x;
    float mean = stats1[c] * (1.f/NMROW);
    float var  = stats1[128+c] * (1.f/NMROW) - mean*mean;
    float scale = g[c] * rsqrtf(var + EPSBN);
    bn1ss[c] = scale;
    bn1ss[128+c] = b[c] - mean*scale;
}

__global__ void k_bn2stats(const float* __restrict__ nsum, float* __restrict__ stats2)
{
    __shared__ float ls[256], ls2[256];
    int tid = threadIdx.x;
    int g = blockIdx.x*256 + tid;       // 1024 blocks x 256
    int c = g & 63;
    int chunk = g >> 6;                 // 4096 chunks x 16 rows
    float s=0.f, s2=0.f;
    for (int i = 0; i < 16; ++i) {
        float v = nsum[(chunk*16 + i)*64 + c];
        s += v; s2 += v*v;
    }
    ls[tid]=s; ls2[tid]=s2; __syncthreads();
    if (tid < 128){ ls[tid]+=ls[tid+128]; ls2[tid]+=ls2[tid+128]; } __syncthreads();
    if (tid < 64){
        atomicAdd(&stats2[tid],    ls[tid]+ls[tid+64]);
        atomicAdd(&stats2[64+tid], ls2[tid]+ls2[tid+64]);
    }
}

__global__ void k_update(float* __restrict__ afea, short* __restrict__ abf,
                         const float* __restrict__ nsum,
                         const float* __restrict__ stats2,
                         const float* __restrict__ g2, const float* __restrict__ b2)
{
    int g = blockIdx.x*256 + threadIdx.x;   // 16384 blocks
    int c = g & 63;
    float mean = stats2[c] * (1.f/NATOM);
    float var  = stats2[64+c] * (1.f/NATOM) - mean*mean;
    float scale = g2[c]*rsqrtf(var + EPSBN);
    float shift = b2[c] - mean*scale;
    float ns = nsum[g]*scale + shift;
    float a = afea[g];
    float v = softplusf_(a + ns) + a;       // afea == identity invariant
    afea[g] = v; abf[g] = f2bf(v);
}

__global__ void k_pool(const float* __restrict__ afea, const int* __restrict__ cidx,
                       float* __restrict__ pool, float* __restrict__ cnt)
{
    int g = blockIdx.x*256 + threadIdx.x;   // 1024 blocks
    int c = g & 63; int chunk = g >> 6;     // 4096 chunks x 16 atoms
    float run = 0.f, rc = 0.f; int cur = -1;
    for (int i = 0; i < 16; ++i) {
        int a = chunk*16 + i;
        int cr = cidx[a];
        float v = afea[a*64 + c];
        if (cr != cur) {
            if (cur >= 0) { atomicAdd(&pool[cur*64+c], run); if (c==0) atomicAdd(&cnt[cur], rc); }
            run = 0.f; rc = 0.f; cur = cr;
        }
        run += v; rc += 1.f;
    }
    atomicAdd(&pool[cur*64+c], run); if (c==0) atomicAdd(&cnt[cur], rc);
}

__global__ void k_head(const float* __restrict__ pool, const float* __restrict__ cnt,
                       const float* __restrict__ fc1w, const float* __restrict__ fc1b,
                       const float* __restrict__ o1w, const float* __restrict__ o1b,
                       const float* __restrict__ o2w, const float* __restrict__ o2b,
                       float* __restrict__ dout)
{
    __shared__ float spv[64], crys[128], h1[64];
    int b = blockIdx.x, tid = threadIdx.x;
    if (tid < 64) {
        float ct = fmaxf(cnt[b], 1.f);
        spv[tid] = softplusf_(pool[b*64+tid] / ct);
    }
    __syncthreads();
    float a = fc1b[tid];
    for (int k = 0; k < 64; ++k) a += spv[k] * fc1w[k*128 + tid];
    float v = softplusf_(a);
    crys[tid] = v;
    dout[NCRYS + b*128 + tid] = v;
    __syncthreads();
    if (tid < 64) {
        float a2 = o1b[tid];
        for (int k = 0; k < 128; ++k) a2 += crys[k] * o1w[k*64 + tid];
        h1[tid] = softplusf_(a2) * o2w[tid];
    }
    __syncthreads();
    if (tid == 0) {
        float s = o2b[0];
        for (int j = 0; j < 64; ++j) s += h1[j];
        dout[b] = s;
    }
}

extern "C" void kernel_launch(void* const* d_in, const int* in_sizes, int n_in,
                              void* d_out, int out_size, void* d_ws, size_t ws_size,
                              hipStream_t stream)
{
    const float* atom_fea = (const float*)d_in[0];
    const float* nbr_fea  = (const float*)d_in[1];
    const int*   nbr_idx  = (const int*)d_in[2];
    const int*   cidx     = (const int*)d_in[3];
    const float* emb_w    = (const float*)d_in[4];
    const float* emb_b    = (const float*)d_in[5];
    const float* cfw      = (const float*)d_in[6];
    const float* cfb      = (const float*)d_in[7];
    const float* bn1g     = (const float*)d_in[8];
    const float* bn1b     = (const float*)d_in[9];
    const float* bn2g     = (const float*)d_in[10];
    const float* bn2b     = (const float*)d_in[11];
    const float* fc1w     = (const float*)d_in[12];
    const float* fc1b     = (const float*)d_in[13];
    const float* o1w      = (const float*)d_in[14];
    const float* o1b      = (const float*)d_in[15];
    const float* o2w      = (const float*)d_in[16];
    const float* o2b      = (const float*)d_in[17];

    float* ws    = (float*)d_ws;
    float* afea  = ws;                         // [0, 4194304)
    float* nsum  = ws + 4194304;               // [4194304, 8388608)
    short* abf   = (short*)(ws + 8388608);     // 4194304 bf16 -> 2097152 floats
    short* nbf   = (short*)(ws + 10485760);    // NMROW*48 bf16 -> 18874368 floats
    short* wt2   = (short*)(ws + 29360128);    // 24576 bf16 -> 12288 floats
    float* stats = ws + 29372416;              // 3 layers x 640
    float* pool  = ws + 29374336;              // 1024*64
    float* cnt   = ws + 29439872;              // 1024

    hipMemsetAsync(stats, 0, (1920 + 65536 + 1024)*sizeof(float), stream);

    k_prep_nbr<<<(NMROW*NBP)/256, 256, 0, stream>>>(nbr_fea, nbf);
    k_embed<<<2048, 256, 0, stream>>>(atom_fea, emb_w, emb_b, afea, abf);

    for (int L = 0; L < 3; ++L) {
        float* st1 = stats + L*640;
        float* ss  = st1 + 256;
        float* st2 = st1 + 512;
        k_prep_w<<<96, 256, 0, stream>>>(cfw + L*169*128, wt2);
        k_conv<0><<<1024, 256, 0, stream>>>(abf, nbf, nbr_idx, wt2, cfb + L*128, st1, nullptr, nullptr);
        k_bn1fin<<<1, 128, 0, stream>>>(st1, bn1g + L*128, bn1b + L*128, ss);
        k_conv<1><<<1024, 256, 0, stream>>>(abf, nbf, nbr_idx, wt2, cfb + L*128, nullptr, ss, nsum);
        k_bn2stats<<<1024, 256, 0, stream>>>(nsum, st2);
        k_update<<<16384, 256, 0, stream>>>(afea, abf, nsum, st2, bn2g + L*64, bn2b + L*64);
    }
    k_pool<<<1024, 256, 0, stream>>>(afea, cidx, pool, cnt);
    k_head<<<NCRYS, 128, 0, stream>>>(pool, cnt, fc1w, fc1b, o1w, o1b, o2w, o2b, (float*)d_out);
}

// Round 4
// 1081.756 us; speedup vs baseline: 4.1088x; 1.2824x over previous
//
#include <hip/hip_runtime.h>

#define NATOM 65536
#define MNBR 12
#define NMROW (NATOM*MNBR)      // 786432
#define ORIG 92
#define NBRF 41
#define AF 64
#define HF 128
#define NCRYS 1024
#define NTILES (NMROW/96)       // 8192 tiles of 96 rows (8 atoms)
#define EPSBN 1e-5f
#define NBP 48                  // padded edge width (bf16)

typedef __attribute__((ext_vector_type(8))) short short8;
typedef __attribute__((ext_vector_type(4))) float floatx4;

__device__ __forceinline__ float softplusf_(float x){
    return fmaxf(x,0.f) + __logf(1.f + __expf(-fabsf(x)));
}
__device__ __forceinline__ float sigmoidf_(float x){
    return __builtin_amdgcn_rcpf(1.f + __expf(-x));
}
__device__ __forceinline__ short f2bf(float x){
    unsigned u = __float_as_uint(x);
    u += 0x7fffu + ((u >> 16) & 1u);   // RNE
    return (short)(u >> 16);
}

// ---------------- embedding: afea = atom_fea @ emb_w + emb_b ----------------
__global__ void k_embed(const float* __restrict__ atom_fea, const float* __restrict__ emb_w,
                        const float* __restrict__ emb_b, float* __restrict__ afea,
                        short* __restrict__ abf)
{
    __shared__ float wl[ORIG*AF];
    __shared__ float bl[AF];
    __shared__ float rows[4*ORIG];
    int tid = threadIdx.x;
    for (int i = tid; i < ORIG*AF; i += 256) wl[i] = emb_w[i];
    if (tid < AF) bl[tid] = emb_b[tid];
    __syncthreads();
    for (int t = blockIdx.x; t < NATOM/4; t += gridDim.x) {
        for (int i = tid; i < 4*ORIG; i += 256) rows[i] = atom_fea[t*4*ORIG + i];
        __syncthreads();
        int r = tid >> 6, c = tid & 63;
        float acc = bl[c];
        const float* rp = &rows[r*ORIG];
        #pragma unroll 4
        for (int k = 0; k < ORIG; ++k) acc += rp[k] * wl[k*AF + c];
        int n = t*4 + r;
        afea[n*AF + c] = acc;
        abf[n*AF + c] = f2bf(acc);
        __syncthreads();
    }
}

// ------------- one-time: nbr_fea fp32 [NM][41] -> bf16 padded [NM][48] -------------
__global__ void k_prep_nbr(const float* __restrict__ nbr_fea, short* __restrict__ nbf)
{
    int g = blockIdx.x*256 + threadIdx.x;   // NMROW*NBP threads
    int row = g / NBP, k = g % NBP;
    float v = (k < NBRF) ? nbr_fea[row*NBRF + k] : 0.f;
    nbf[g] = f2bf(v);
}

// ------------- per-layer: W fp32 [169][128] -> bf16 fragments [ks][q][c][j] -------------
__global__ void k_prep_w(const float* __restrict__ W, short* __restrict__ wt2)
{
    int g = blockIdx.x*256 + threadIdx.x;   // 24576 threads
    int j = g & 7, c = (g >> 3) & 127, q = (g >> 10) & 3, ks = g >> 12;
    int k = ks*32 + q*8 + j;
    wt2[g] = (k < 169) ? f2bf(W[k*128 + c]) : (short)0;
}

// ---------------- conv GEMM: gated = [self|nbr|edge] @ W + b ----------------
// Wave task = 48 rows (4 atoms) x 16 paired channels (filt c = chq*16+l15, core c+64).
// Block = 4 waves sharing the same 48 rows (chq = wave). bt = blockIdx-stride task:
// tile = bt>>1, rh = bt&1. No __syncthreads anywhere; wave-private LDS for m-sum.
// PASS2=0: per-channel sum/sumsq of gated -> stats1 (reg-accumulated, atomics at end).
// PASS2=1: BN1 + sigmoid*softplus, per-atom m-sum -> nsum (direct stores).
template<int PASS2>
__global__ __launch_bounds__(256, 4)
void k_conv(const short* __restrict__ abf, const short* __restrict__ nbf,
            const int* __restrict__ nbr_idx, const short* __restrict__ wt2,
            const float* __restrict__ bias,
            float* __restrict__ stats1, const float* __restrict__ bn1ss,
            float* __restrict__ nsum)
{
    __shared__ float pbuf[PASS2 ? 4*12*17 : 4];   // wave-private [12][17]

    int tid = threadIdx.x;
    int lane = tid & 63, wave = tid >> 6;
    int l15 = lane & 15, q = lane >> 4;
    int cf = wave*16 + l15;       // filt channel (0..63)
    int cc = 64 + cf;             // core channel (64..127)

    short8 wf[6][2];
    #pragma unroll
    for (int ks = 0; ks < 6; ++ks) {
        wf[ks][0] = *(const short8*)(wt2 + ((ks*4+q)*128 + cf)*8);
        wf[ks][1] = *(const short8*)(wt2 + ((ks*4+q)*128 + cc)*8);
    }
    float bs0 = bias[cf], bs1 = bias[cc];
    float sc0=0.f, sh0=0.f, sc1=0.f, sh1=0.f;
    if (PASS2) { sc0=bn1ss[cf]; sh0=bn1ss[128+cf]; sc1=bn1ss[cc]; sh1=bn1ss[128+cc]; }

    float s_acc[2]={0.f,0.f}, s2_acc[2]={0.f,0.f};
    const short8 zf = {0,0,0,0,0,0,0,0};
    float* pb = pbuf + wave*(12*17);

    for (int bt = blockIdx.x; bt < NTILES*2; bt += gridDim.x) {
        int tile = bt >> 1, rh = bt & 1;
        int Rb = tile*96 + rh*48 + l15;

        int nj[3];
        #pragma unroll
        for (int rt = 0; rt < 3; ++rt) nj[rt] = nbr_idx[Rb + rt*16];

        floatx4 acc[3][2];
        #pragma unroll
        for (int rt=0; rt<3; ++rt) {
            acc[rt][0] = (floatx4){bs0,bs0,bs0,bs0};
            acc[rt][1] = (floatx4){bs1,bs1,bs1,bs1};
        }

        // self (ks 0,1) + edge (ks 4,5) first — no dependency on nj
        short8 sv[3][2], ev[3][2];
        #pragma unroll
        for (int rt = 0; rt < 3; ++rt) {
            const short* sp = abf + (unsigned)((Rb + rt*16)/12u)*64u + q*8;
            sv[rt][0] = *(const short8*)sp;
            sv[rt][1] = *(const short8*)(sp + 32);
            const short* ep = nbf + (unsigned)(Rb + rt*16)*NBP + q*8;
            ev[rt][0] = *(const short8*)ep;
            ev[rt][1] = (q < 2) ? *(const short8*)(ep + 32) : zf;
        }
        #pragma unroll
        for (int rt = 0; rt < 3; ++rt)
            #pragma unroll
            for (int ct = 0; ct < 2; ++ct) {
                acc[rt][ct] = __builtin_amdgcn_mfma_f32_16x16x32_bf16(sv[rt][0], wf[0][ct], acc[rt][ct], 0,0,0);
                acc[rt][ct] = __builtin_amdgcn_mfma_f32_16x16x32_bf16(sv[rt][1], wf[1][ct], acc[rt][ct], 0,0,0);
                acc[rt][ct] = __builtin_amdgcn_mfma_f32_16x16x32_bf16(ev[rt][0], wf[4][ct], acc[rt][ct], 0,0,0);
                acc[rt][ct] = __builtin_amdgcn_mfma_f32_16x16x32_bf16(ev[rt][1], wf[5][ct], acc[rt][ct], 0,0,0);
            }

        // neighbor gather (ks 2,3)
        short8 nv[3][2];
        #pragma unroll
        for (int rt = 0; rt < 3; ++rt) {
            const short* np = abf + (unsigned)nj[rt]*64u + q*8;
            nv[rt][0] = *(const short8*)np;
            nv[rt][1] = *(const short8*)(np + 32);
        }
        #pragma unroll
        for (int rt = 0; rt < 3; ++rt)
            #pragma unroll
            for (int ct = 0; ct < 2; ++ct) {
                acc[rt][ct] = __builtin_amdgcn_mfma_f32_16x16x32_bf16(nv[rt][0], wf[2][ct], acc[rt][ct], 0,0,0);
                acc[rt][ct] = __builtin_amdgcn_mfma_f32_16x16x32_bf16(nv[rt][1], wf[3][ct], acc[rt][ct], 0,0,0);
            }

        if (!PASS2) {
            #pragma unroll
            for (int ct=0; ct<2; ++ct)
                #pragma unroll
                for (int rt=0; rt<3; ++rt)
                    #pragma unroll
                    for (int r=0; r<4; ++r) {
                        float v = acc[rt][ct][r];
                        s_acc[ct] += v; s2_acc[ct] += v*v;
                    }
        } else {
            // 4-row partials: group g = rt*4+q holds rows g*4..g*4+3; atom = g/3
            #pragma unroll
            for (int rt=0; rt<3; ++rt) {
                float part = 0.f;
                #pragma unroll
                for (int r=0; r<4; ++r) {
                    float f = acc[rt][0][r]*sc0 + sh0;
                    float g = acc[rt][1][r]*sc1 + sh1;
                    part += sigmoidf_(f) * softplusf_(g);
                }
                pb[(rt*4+q)*17 + l15] = part;
            }
            // wave-private: lgkmcnt ordering suffices, no barrier
            int a = lane >> 4, c16 = lane & 15;
            float s = pb[(3*a+0)*17 + c16] + pb[(3*a+1)*17 + c16] + pb[(3*a+2)*17 + c16];
            nsum[(tile*8 + rh*4 + a)*AF + wave*16 + c16] = s;
        }
    }

    if (!PASS2) {
        #pragma unroll
        for (int ct=0; ct<2; ++ct) {
            float s = s_acc[ct], s2 = s2_acc[ct];
            s  += __shfl_xor(s, 16);  s  += __shfl_xor(s, 32);
            s2 += __shfl_xor(s2, 16); s2 += __shfl_xor(s2, 32);
            if (q == 0) {
                int c = ct ? cc : cf;
                atomicAdd(&stats1[c], s);
                atomicAdd(&stats1[128 + c], s2);
            }
        }
    }
}

__global__ void k_bn1fin(const float* __restrict__ stats1, const float* __restrict__ g,
                         const float* __restrict__ b, float* __restrict__ bn1ss)
{
    int c = threadIdx.x;
    float mean = stats1[c] * (1.f/NMROW);
    float var  = stats1[128+c] * (1.f/NMROW) - mean*mean;
    float scale = g[c] * rsqrtf(var + EPSBN);
    bn1ss[c] = scale;
    bn1ss[128+c] = b[c] - mean*scale;
}

__global__ void k_bn2stats(const float* __restrict__ nsum, float* __restrict__ stats2)
{
    __shared__ float ls[256], ls2[256];
    int tid = threadIdx.x;
    int g = blockIdx.x*256 + tid;       // 1024 blocks x 256
    int c = g & 63;
    int chunk = g >> 6;                 // 4096 chunks x 16 rows
    float s=0.f, s2=0.f;
    for (int i = 0; i < 16; ++i) {
        float v = nsum[(chunk*16 + i)*64 + c];
        s += v; s2 += v*v;
    }
    ls[tid]=s; ls2[tid]=s2; __syncthreads();
    if (tid < 128){ ls[tid]+=ls[tid+128]; ls2[tid]+=ls2[tid+128]; } __syncthreads();
    if (tid < 64){
        atomicAdd(&stats2[tid],    ls[tid]+ls[tid+64]);
        atomicAdd(&stats2[64+tid], ls2[tid]+ls2[tid+64]);
    }
}

__global__ void k_update(float* __restrict__ afea, short* __restrict__ abf,
                         const float* __restrict__ nsum,
                         const float* __restrict__ stats2,
                         const float* __restrict__ g2, const float* __restrict__ b2)
{
    int g = blockIdx.x*256 + threadIdx.x;   // 16384 blocks
    int c = g & 63;
    float mean = stats2[c] * (1.f/NATOM);
    float var  = stats2[64+c] * (1.f/NATOM) - mean*mean;
    float scale = g2[c]*rsqrtf(var + EPSBN);
    float shift = b2[c] - mean*scale;
    float ns = nsum[g]*scale + shift;
    float a = afea[g];
    float v = softplusf_(a + ns) + a;       // afea == identity invariant
    afea[g] = v; abf[g] = f2bf(v);
}

__global__ void k_pool(const float* __restrict__ afea, const int* __restrict__ cidx,
                       float* __restrict__ pool, float* __restrict__ cnt)
{
    int g = blockIdx.x*256 + threadIdx.x;   // 1024 blocks
    int c = g & 63; int chunk = g >> 6;     // 4096 chunks x 16 atoms
    float run = 0.f, rc = 0.f; int cur = -1;
    for (int i = 0; i < 16; ++i) {
        int a = chunk*16 + i;
        int cr = cidx[a];
        float v = afea[a*64 + c];
        if (cr != cur) {
            if (cur >= 0) { atomicAdd(&pool[cur*64+c], run); if (c==0) atomicAdd(&cnt[cur], rc); }
            run = 0.f; rc = 0.f; cur = cr;
        }
        run += v; rc += 1.f;
    }
    atomicAdd(&pool[cur*64+c], run); if (c==0) atomicAdd(&cnt[cur], rc);
}

__global__ void k_head(const float* __restrict__ pool, const float* __restrict__ cnt,
                       const float* __restrict__ fc1w, const float* __restrict__ fc1b,
                       const float* __restrict__ o1w, const float* __restrict__ o1b,
                       const float* __restrict__ o2w, const float* __restrict__ o2b,
                       float* __restrict__ dout)
{
    __shared__ float spv[64], crys[128], h1[64];
    int b = blockIdx.x, tid = threadIdx.x;
    if (tid < 64) {
        float ct = fmaxf(cnt[b], 1.f);
        spv[tid] = softplusf_(pool[b*64+tid] / ct);
    }
    __syncthreads();
    float a = fc1b[tid];
    for (int k = 0; k < 64; ++k) a += spv[k] * fc1w[k*128 + tid];
    float v = softplusf_(a);
    crys[tid] = v;
    dout[NCRYS + b*128 + tid] = v;
    __syncthreads();
    if (tid < 64) {
        float a2 = o1b[tid];
        for (int k = 0; k < 128; ++k) a2 += crys[k] * o1w[k*64 + tid];
        h1[tid] = softplusf_(a2) * o2w[tid];
    }
    __syncthreads();
    if (tid == 0) {
        float s = o2b[0];
        for (int j = 0; j < 64; ++j) s += h1[j];
        dout[b] = s;
    }
}

extern "C" void kernel_launch(void* const* d_in, const int* in_sizes, int n_in,
                              void* d_out, int out_size, void* d_ws, size_t ws_size,
                              hipStream_t stream)
{
    const float* atom_fea = (const float*)d_in[0];
    const float* nbr_fea  = (const float*)d_in[1];
    const int*   nbr_idx  = (const int*)d_in[2];
    const int*   cidx     = (const int*)d_in[3];
    const float* emb_w    = (const float*)d_in[4];
    const float* emb_b    = (const float*)d_in[5];
    const float* cfw      = (const float*)d_in[6];
    const float* cfb      = (const float*)d_in[7];
    const float* bn1g     = (const float*)d_in[8];
    const float* bn1b     = (const float*)d_in[9];
    const float* bn2g     = (const float*)d_in[10];
    const float* bn2b     = (const float*)d_in[11];
    const float* fc1w     = (const float*)d_in[12];
    const float* fc1b     = (const float*)d_in[13];
    const float* o1w      = (const float*)d_in[14];
    const float* o1b      = (const float*)d_in[15];
    const float* o2w      = (const float*)d_in[16];
    const float* o2b      = (const float*)d_in[17];

    float* ws    = (float*)d_ws;
    float* afea  = ws;                         // [0, 4194304)
    float* nsum  = ws + 4194304;               // [4194304, 8388608)
    short* abf   = (short*)(ws + 8388608);     // 4194304 bf16
    short* nbf   = (short*)(ws + 10485760);    // NMROW*48 bf16
    short* wt2   = (short*)(ws + 29360128);    // 24576 bf16
    float* stats = ws + 29372416;              // 3 layers x 640
    float* pool  = ws + 29374336;              // 1024*64
    float* cnt   = ws + 29439872;              // 1024

    hipMemsetAsync(stats, 0, (1920 + 65536 + 1024)*sizeof(float), stream);

    k_prep_nbr<<<(NMROW*NBP)/256, 256, 0, stream>>>(nbr_fea, nbf);
    k_embed<<<2048, 256, 0, stream>>>(atom_fea, emb_w, emb_b, afea, abf);

    for (int L = 0; L < 3; ++L) {
        float* st1 = stats + L*640;
        float* ss  = st1 + 256;
        float* st2 = st1 + 512;
        k_prep_w<<<96, 256, 0, stream>>>(cfw + L*169*128, wt2);
        k_conv<0><<<2048, 256, 0, stream>>>(abf, nbf, nbr_idx, wt2, cfb + L*128, st1, nullptr, nullptr);
        k_bn1fin<<<1, 128, 0, stream>>>(st1, bn1g + L*128, bn1b + L*128, ss);
        k_conv<1><<<2048, 256, 0, stream>>>(abf, nbf, nbr_idx, wt2, cfb + L*128, nullptr, ss, nsum);
        k_bn2stats<<<1024, 256, 0, stream>>>(nsum, st2);
        k_update<<<16384, 256, 0, stream>>>(afea, abf, nsum, st2, bn2g + L*64, bn2b + L*64);
    }
    k_pool<<<1024, 256, 0, stream>>>(afea, cidx, pool, cnt);
    k_head<<<NCRYS, 128, 0, stream>>>(pool, cnt, fc1w, fc1b, o1w, o1b, o2w, o2b, (float*)d_out);
}

// Round 5
// 963.361 us; speedup vs baseline: 4.6138x; 1.1229x over previous
//
#include <hip/hip_runtime.h>

#define NATOM 65536
#define MNBR 12
#define NMROW (NATOM*MNBR)      // 786432
#define ORIG 92
#define NBRF 41
#define AF 64
#define HF 128
#define NCRYS 1024
#define NTILES (NMROW/96)       // 8192 tiles of 96 rows (8 atoms)
#define EPSBN 1e-5f
#define NBP 48                  // padded edge width (bf16)
#define CGRID 2048

typedef __attribute__((ext_vector_type(8))) short short8;
typedef __attribute__((ext_vector_type(4))) float floatx4;

__device__ __forceinline__ float softplusf_(float x){
    return fmaxf(x,0.f) + __logf(1.f + __expf(-fabsf(x)));
}
__device__ __forceinline__ float sigmoidf_(float x){
    return __builtin_amdgcn_rcpf(1.f + __expf(-x));
}
__device__ __forceinline__ short f2bf(float x){
    unsigned u = __float_as_uint(x);
    u += 0x7fffu + ((u >> 16) & 1u);   // RNE
    return (short)(u >> 16);
}

// ---------------- embedding: afea = atom_fea @ emb_w + emb_b ----------------
__global__ void k_embed(const float* __restrict__ atom_fea, const float* __restrict__ emb_w,
                        const float* __restrict__ emb_b, float* __restrict__ afea,
                        short* __restrict__ abf)
{
    __shared__ float wl[ORIG*AF];
    __shared__ float bl[AF];
    __shared__ float rows[4*ORIG];
    int tid = threadIdx.x;
    for (int i = tid; i < ORIG*AF; i += 256) wl[i] = emb_w[i];
    if (tid < AF) bl[tid] = emb_b[tid];
    __syncthreads();
    for (int t = blockIdx.x; t < NATOM/4; t += gridDim.x) {
        for (int i = tid; i < 4*ORIG; i += 256) rows[i] = atom_fea[t*4*ORIG + i];
        __syncthreads();
        int r = tid >> 6, c = tid & 63;
        float acc = bl[c];
        const float* rp = &rows[r*ORIG];
        #pragma unroll 4
        for (int k = 0; k < ORIG; ++k) acc += rp[k] * wl[k*AF + c];
        int n = t*4 + r;
        afea[n*AF + c] = acc;
        abf[n*AF + c] = f2bf(acc);
        __syncthreads();
    }
}

// ------------- one-time: nbr_fea fp32 [NM][41] -> bf16 padded [NM][48] -------------
__global__ void k_prep_nbr(const float* __restrict__ nbr_fea, short* __restrict__ nbf)
{
    int g = blockIdx.x*256 + threadIdx.x;   // NMROW*NBP threads
    int row = g / NBP, k = g % NBP;
    float v = (k < NBRF) ? nbr_fea[row*NBRF + k] : 0.f;
    nbf[g] = f2bf(v);
}

// ------------- per-layer: W fp32 [169][128] -> bf16 fragments [ks][q][c][j] -------------
__global__ void k_prep_w(const float* __restrict__ W, short* __restrict__ wt2)
{
    int g = blockIdx.x*256 + threadIdx.x;   // 24576 threads
    int j = g & 7, c = (g >> 3) & 127, q = (g >> 10) & 3, ks = g >> 12;
    int k = ks*32 + q*8 + j;
    wt2[g] = (k < 169) ? f2bf(W[k*128 + c]) : (short)0;
}

// ---------------- conv GEMM: gated = [self|nbr|edge] @ W + b ----------------
// Task = 48 rows (4 atoms) x 128 ch; block's 4 waves share rows, wave owns 16
// paired channels (filt cf = wave*16+l15, core cf+64). Nbr+edge rows staged in
// LDS once per task (kills 4x redundant global reads); self rows direct (L1-hot).
// W fragments register-resident. 2 barriers/task; wave-private epilogue LDS.
// PASS2=0: per-channel sum/sumsq of gated -> stats1.
// PASS2=1: BN1 + sigmoid*softplus, m-sum -> nsum; nsum sum/sumsq -> stats2.
template<int PASS2>
__global__ __launch_bounds__(256, 4)
void k_conv(const short* __restrict__ abf, const short* __restrict__ nbf,
            const int* __restrict__ nbr_idx, const short* __restrict__ wt2,
            const float* __restrict__ bias,
            float* __restrict__ stats1, const float* __restrict__ bn1ss,
            float* __restrict__ nsum, float* __restrict__ stats2)
{
    __shared__ __align__(16) short stg[6144];   // nbr 48x(64|pad72) @0, edge 48x(48|pad56) @3456
    __shared__ float pbuf[4*12*17];             // wave-private m-sum buffers

    int tid = threadIdx.x;
    int lane = tid & 63, wave = tid >> 6;
    int l15 = lane & 15, q = lane >> 4;
    int cf = wave*16 + l15;       // filt channel (0..63)
    int cc = 64 + cf;             // core channel (64..127)

    short8 wf[6][2];
    #pragma unroll
    for (int ks = 0; ks < 6; ++ks) {
        wf[ks][0] = *(const short8*)(wt2 + ((ks*4+q)*128 + cf)*8);
        wf[ks][1] = *(const short8*)(wt2 + ((ks*4+q)*128 + cc)*8);
    }
    float bs0 = bias[cf], bs1 = bias[cc];
    float sc0=0.f, sh0=0.f, sc1=0.f, sh1=0.f;
    if (PASS2) { sc0=bn1ss[cf]; sh0=bn1ss[128+cf]; sc1=bn1ss[cc]; sh1=bn1ss[128+cc]; }

    float s_acc[2]={0.f,0.f}, s2_acc[2]={0.f,0.f};
    float st2s = 0.f, st2q = 0.f;
    const short8 zf = {0,0,0,0,0,0,0,0};
    float* pb = pbuf + wave*(12*17);

    for (int bt = blockIdx.x; bt < NTILES*2; bt += CGRID) {
        int tile = bt >> 1, rh = bt & 1;
        int R0 = tile*96 + rh*48;

        __syncthreads();   // previous task's staged-LDS reads complete
        // stage: nbr rows (gather via nbr_idx) + edge rows
        #pragma unroll
        for (int it = 0; it < 3; ++it) {
            int i = tid + it*256;
            if (i < 384) {
                int row = i >> 3, c = i & 7;
                int j = nbr_idx[R0 + row];
                *(short8*)(stg + row*72 + c*8) = *(const short8*)(abf + (unsigned)j*64u + c*8);
            } else if (i < 672) {
                int j2 = i - 384;
                int row = j2 / 6, c = j2 % 6;
                *(short8*)(stg + 3456 + row*56 + c*8) =
                    *(const short8*)(nbf + (unsigned)(R0 + row)*48u + c*8);
            }
        }
        // self rows: direct global (4 atoms, L1-hot, broadcast-heavy)
        short8 sv[3][2];
        #pragma unroll
        for (int rt = 0; rt < 3; ++rt) {
            const short* sp = abf + (unsigned)((R0 + rt*16 + l15)/12u)*64u + q*8;
            sv[rt][0] = *(const short8*)sp;
            sv[rt][1] = *(const short8*)(sp + 32);
        }
        __syncthreads();   // staging visible

        floatx4 acc[3][2];
        #pragma unroll
        for (int rt=0; rt<3; ++rt) {
            acc[rt][0] = (floatx4){bs0,bs0,bs0,bs0};
            acc[rt][1] = (floatx4){bs1,bs1,bs1,bs1};
        }

        #pragma unroll
        for (int rt = 0; rt < 3; ++rt) {
            int r = rt*16 + l15;
            short8 nv0 = *(const short8*)(stg + r*72 + q*8);
            short8 nv1 = *(const short8*)(stg + r*72 + 32 + q*8);
            short8 ev0 = *(const short8*)(stg + 3456 + r*56 + q*8);
            short8 ev1 = (q < 2) ? *(const short8*)(stg + 3456 + r*56 + 32 + q*8) : zf;
            #pragma unroll
            for (int ct = 0; ct < 2; ++ct) {
                acc[rt][ct] = __builtin_amdgcn_mfma_f32_16x16x32_bf16(sv[rt][0], wf[0][ct], acc[rt][ct], 0,0,0);
                acc[rt][ct] = __builtin_amdgcn_mfma_f32_16x16x32_bf16(sv[rt][1], wf[1][ct], acc[rt][ct], 0,0,0);
                acc[rt][ct] = __builtin_amdgcn_mfma_f32_16x16x32_bf16(nv0,      wf[2][ct], acc[rt][ct], 0,0,0);
                acc[rt][ct] = __builtin_amdgcn_mfma_f32_16x16x32_bf16(nv1,      wf[3][ct], acc[rt][ct], 0,0,0);
                acc[rt][ct] = __builtin_amdgcn_mfma_f32_16x16x32_bf16(ev0,      wf[4][ct], acc[rt][ct], 0,0,0);
                acc[rt][ct] = __builtin_amdgcn_mfma_f32_16x16x32_bf16(ev1,      wf[5][ct], acc[rt][ct], 0,0,0);
            }
        }

        if (!PASS2) {
            #pragma unroll
            for (int ct=0; ct<2; ++ct)
                #pragma unroll
                for (int rt=0; rt<3; ++rt)
                    #pragma unroll
                    for (int r=0; r<4; ++r) {
                        float v = acc[rt][ct][r];
                        s_acc[ct] += v; s2_acc[ct] += v*v;
                    }
        } else {
            // 4-row partials: group g = rt*4+q holds rows g*4..g*4+3 (4 | 12 => atom-aligned)
            #pragma unroll
            for (int rt=0; rt<3; ++rt) {
                float part = 0.f;
                #pragma unroll
                for (int r=0; r<4; ++r) {
                    float f = acc[rt][0][r]*sc0 + sh0;
                    float g = acc[rt][1][r]*sc1 + sh1;
                    part += sigmoidf_(f) * softplusf_(g);
                }
                pb[(rt*4+q)*17 + l15] = part;
            }
            // wave-private LDS: lgkmcnt ordering suffices, no barrier
            int a = lane >> 4, c16 = lane & 15;
            float s = pb[(3*a+0)*17 + c16] + pb[(3*a+1)*17 + c16] + pb[(3*a+2)*17 + c16];
            nsum[(tile*8 + rh*4 + a)*AF + wave*16 + c16] = s;
            st2s += s; st2q += s*s;
        }
    }

    if (!PASS2) {
        #pragma unroll
        for (int ct=0; ct<2; ++ct) {
            float s = s_acc[ct], s2 = s2_acc[ct];
            s  += __shfl_xor(s, 16);  s  += __shfl_xor(s, 32);
            s2 += __shfl_xor(s2, 16); s2 += __shfl_xor(s2, 32);
            if (q == 0) {
                int c = ct ? cc : cf;
                atomicAdd(&stats1[c], s);
                atomicAdd(&stats1[128 + c], s2);
            }
        }
    } else {
        // lanes {c16, 16+c16, 32+c16, 48+c16} hold partials for channel wave*16+c16
        st2s += __shfl_xor(st2s, 16); st2s += __shfl_xor(st2s, 32);
        st2q += __shfl_xor(st2q, 16); st2q += __shfl_xor(st2q, 32);
        if (q == 0) {
            atomicAdd(&stats2[cf], st2s);
            atomicAdd(&stats2[64 + cf], st2q);
        }
    }
}

__global__ void k_bn1fin(const float* __restrict__ stats1, const float* __restrict__ g,
                         const float* __restrict__ b, float* __restrict__ bn1ss)
{
    int c = threadIdx.x;
    float mean = stats1[c] * (1.f/NMROW);
    float var  = stats1[128+c] * (1.f/NMROW) - mean*mean;
    float scale = g[c] * rsqrtf(var + EPSBN);
    bn1ss[c] = scale;
    bn1ss[128+c] = b[c] - mean*scale;
}

__global__ void k_update(float* __restrict__ afea, short* __restrict__ abf,
                         const float* __restrict__ nsum,
                         const float* __restrict__ stats2,
                         const float* __restrict__ g2, const float* __restrict__ b2)
{
    int g = blockIdx.x*256 + threadIdx.x;   // 16384 blocks
    int c = g & 63;
    float mean = stats2[c] * (1.f/NATOM);
    float var  = stats2[64+c] * (1.f/NATOM) - mean*mean;
    float scale = g2[c]*rsqrtf(var + EPSBN);
    float shift = b2[c] - mean*scale;
    float ns = nsum[g]*scale + shift;
    float a = afea[g];
    float v = softplusf_(a + ns) + a;       // afea == identity invariant
    afea[g] = v; abf[g] = f2bf(v);
}

__global__ void k_pool(const float* __restrict__ afea, const int* __restrict__ cidx,
                       float* __restrict__ pool, float* __restrict__ cnt)
{
    int g = blockIdx.x*256 + threadIdx.x;   // 1024 blocks
    int c = g & 63; int chunk = g >> 6;     // 4096 chunks x 16 atoms
    float run = 0.f, rc = 0.f; int cur = -1;
    for (int i = 0; i < 16; ++i) {
        int a = chunk*16 + i;
        int cr = cidx[a];
        float v = afea[a*64 + c];
        if (cr != cur) {
            if (cur >= 0) { atomicAdd(&pool[cur*64+c], run); if (c==0) atomicAdd(&cnt[cur], rc); }
            run = 0.f; rc = 0.f; cur = cr;
        }
        run += v; rc += 1.f;
    }
    atomicAdd(&pool[cur*64+c], run); if (c==0) atomicAdd(&cnt[cur], rc);
}

__global__ void k_head(const float* __restrict__ pool, const float* __restrict__ cnt,
                       const float* __restrict__ fc1w, const float* __restrict__ fc1b,
                       const float* __restrict__ o1w, const float* __restrict__ o1b,
                       const float* __restrict__ o2w, const float* __restrict__ o2b,
                       float* __restrict__ dout)
{
    __shared__ float spv[64], crys[128], h1[64];
    int b = blockIdx.x, tid = threadIdx.x;
    if (tid < 64) {
        float ct = fmaxf(cnt[b], 1.f);
        spv[tid] = softplusf_(pool[b*64+tid] / ct);
    }
    __syncthreads();
    float a = fc1b[tid];
    for (int k = 0; k < 64; ++k) a += spv[k] * fc1w[k*128 + tid];
    float v = softplusf_(a);
    crys[tid] = v;
    dout[NCRYS + b*128 + tid] = v;
    __syncthreads();
    if (tid < 64) {
        float a2 = o1b[tid];
        for (int k = 0; k < 128; ++k) a2 += crys[k] * o1w[k*64 + tid];
        h1[tid] = softplusf_(a2) * o2w[tid];
    }
    __syncthreads();
    if (tid == 0) {
        float s = o2b[0];
        for (int j = 0; j < 64; ++j) s += h1[j];
        dout[b] = s;
    }
}

extern "C" void kernel_launch(void* const* d_in, const int* in_sizes, int n_in,
                              void* d_out, int out_size, void* d_ws, size_t ws_size,
                              hipStream_t stream)
{
    const float* atom_fea = (const float*)d_in[0];
    const float* nbr_fea  = (const float*)d_in[1];
    const int*   nbr_idx  = (const int*)d_in[2];
    const int*   cidx     = (const int*)d_in[3];
    const float* emb_w    = (const float*)d_in[4];
    const float* emb_b    = (const float*)d_in[5];
    const float* cfw      = (const float*)d_in[6];
    const float* cfb      = (const float*)d_in[7];
    const float* bn1g     = (const float*)d_in[8];
    const float* bn1b     = (const float*)d_in[9];
    const float* bn2g     = (const float*)d_in[10];
    const float* bn2b     = (const float*)d_in[11];
    const float* fc1w     = (const float*)d_in[12];
    const float* fc1b     = (const float*)d_in[13];
    const float* o1w      = (const float*)d_in[14];
    const float* o1b      = (const float*)d_in[15];
    const float* o2w      = (const float*)d_in[16];
    const float* o2b      = (const float*)d_in[17];

    float* ws    = (float*)d_ws;
    float* afea  = ws;                         // [0, 4194304)
    float* nsum  = ws + 4194304;               // [4194304, 8388608)
    short* abf   = (short*)(ws + 8388608);     // 4194304 bf16
    short* nbf   = (short*)(ws + 10485760);    // NMROW*48 bf16
    short* wt2   = (short*)(ws + 29360128);    // 24576 bf16
    float* stats = ws + 29372416;              // 3 layers x 640
    float* pool  = ws + 29374336;              // 1024*64
    float* cnt   = ws + 29439872;              // 1024

    hipMemsetAsync(stats, 0, (1920 + 65536 + 1024)*sizeof(float), stream);

    k_prep_nbr<<<(NMROW*NBP)/256, 256, 0, stream>>>(nbr_fea, nbf);
    k_embed<<<2048, 256, 0, stream>>>(atom_fea, emb_w, emb_b, afea, abf);

    for (int L = 0; L < 3; ++L) {
        float* st1 = stats + L*640;
        float* ss  = st1 + 256;
        float* st2 = st1 + 512;
        k_prep_w<<<96, 256, 0, stream>>>(cfw + L*169*128, wt2);
        k_conv<0><<<CGRID, 256, 0, stream>>>(abf, nbf, nbr_idx, wt2, cfb + L*128, st1, nullptr, nullptr, nullptr);
        k_bn1fin<<<1, 128, 0, stream>>>(st1, bn1g + L*128, bn1b + L*128, ss);
        k_conv<1><<<CGRID, 256, 0, stream>>>(abf, nbf, nbr_idx, wt2, cfb + L*128, nullptr, ss, nsum, st2);
        k_update<<<16384, 256, 0, stream>>>(afea, abf, nsum, st2, bn2g + L*64, bn2b + L*64);
    }
    k_pool<<<1024, 256, 0, stream>>>(afea, cidx, pool, cnt);
    k_head<<<NCRYS, 128, 0, stream>>>(pool, cnt, fc1w, fc1b, o1w, o1b, o2w, o2b, (float*)d_out);
}

// Round 6
// 849.652 us; speedup vs baseline: 5.2313x; 1.1338x over previous
//
#include <hip/hip_runtime.h>

#define NATOM 65536
#define MNBR 12
#define NMROW (NATOM*MNBR)      // 786432
#define ORIG 92
#define NBRF 41
#define AF 64
#define HF 128
#define NCRYS 1024
#define EPSBN 1e-5f
#define NBP 48                  // padded edge width (bf16)
#define CGRID 2048
#define NTASK 16384             // 48-row tasks; 8 per block exactly

typedef __attribute__((ext_vector_type(8))) short short8;
typedef __attribute__((ext_vector_type(4))) float floatx4;

__device__ __forceinline__ float softplusf_(float x){
    return fmaxf(x,0.f) + __logf(1.f + __expf(-fabsf(x)));
}
__device__ __forceinline__ float sigmoidf_(float x){
    return __builtin_amdgcn_rcpf(1.f + __expf(-x));
}
__device__ __forceinline__ short f2bf(float x){
    unsigned u = __float_as_uint(x);
    u += 0x7fffu + ((u >> 16) & 1u);   // RNE
    return (short)(u >> 16);
}

// ---------------- embedding: afea = atom_fea @ emb_w + emb_b ----------------
__global__ void k_embed(const float* __restrict__ atom_fea, const float* __restrict__ emb_w,
                        const float* __restrict__ emb_b, float* __restrict__ afea,
                        short* __restrict__ abf)
{
    __shared__ float wl[ORIG*AF];
    __shared__ float bl[AF];
    __shared__ float rows[4*ORIG];
    int tid = threadIdx.x;
    for (int i = tid; i < ORIG*AF; i += 256) wl[i] = emb_w[i];
    if (tid < AF) bl[tid] = emb_b[tid];
    __syncthreads();
    for (int t = blockIdx.x; t < NATOM/4; t += gridDim.x) {
        for (int i = tid; i < 4*ORIG; i += 256) rows[i] = atom_fea[t*4*ORIG + i];
        __syncthreads();
        int r = tid >> 6, c = tid & 63;
        float acc = bl[c];
        const float* rp = &rows[r*ORIG];
        #pragma unroll 4
        for (int k = 0; k < ORIG; ++k) acc += rp[k] * wl[k*AF + c];
        int n = t*4 + r;
        afea[n*AF + c] = acc;
        abf[n*AF + c] = f2bf(acc);
        __syncthreads();
    }
}

// ------------- one-time: nbr_fea fp32 [NM][41] -> bf16 padded [NM][48] -------------
__global__ void k_prep_nbr(const float* __restrict__ nbr_fea, short* __restrict__ nbf)
{
    int g = blockIdx.x*256 + threadIdx.x;   // NMROW*NBP threads
    int row = g / NBP, k = g % NBP;
    float v = (k < NBRF) ? nbr_fea[row*NBRF + k] : 0.f;
    nbf[g] = f2bf(v);
}

// ------------- per-layer: W fp32 [169][128] -> bf16 fragments [ks][q][c][j] -------------
__global__ void k_prep_w(const float* __restrict__ W, short* __restrict__ wt2)
{
    int g = blockIdx.x*256 + threadIdx.x;   // 24576 threads
    int j = g & 7, c = (g >> 3) & 127, q = (g >> 10) & 3, ks = g >> 12;
    int k = ks*32 + q*8 + j;
    wt2[g] = (k < 169) ? f2bf(W[k*128 + c]) : (short)0;
}

// ---------------- conv GEMM: gated = [self|nbr|edge] @ W + b ----------------
// Task = 48 rows (4 atoms) x 128 ch; block's 4 waves share rows, wave owns 16
// paired channels (filt cf = wave*16+l15, core cf+64). All A-data (nbr gather,
// edge, self) staged in double-buffered LDS; software pipeline: issue task k+1
// global loads -> regs while computing task k from LDS; idx prefetched 2 ahead.
// Exactly 8 tasks/block. One barrier/task. W fragments register-resident.
// PASS2=0: per-channel sum/sumsq of gated -> stats1.
// PASS2=1: BN1 + sigmoid*softplus, m-sum -> nsum; nsum sum/sumsq -> stats2.
template<int PASS2>
__global__ __launch_bounds__(256, 3)
void k_conv(const short* __restrict__ abf, const short* __restrict__ nbf,
            const int* __restrict__ nbr_idx, const short* __restrict__ wt2,
            const float* __restrict__ bias,
            float* __restrict__ stats1, const float* __restrict__ bn1ss,
            float* __restrict__ nsum, float* __restrict__ stats2)
{
    // per buffer: nbr 48x72 @0, edge 48x56 @3456, self 4x72 @6144  (6432 shorts)
    __shared__ __align__(16) short stg[2][6432];
    __shared__ float pbuf[4*12*17];             // wave-private m-sum buffers

    int tid = threadIdx.x;
    int lane = tid & 63, wave = tid >> 6;
    int l15 = lane & 15, q = lane >> 4;
    int cf = wave*16 + l15;       // filt channel (0..63)
    int cc = 64 + cf;             // core channel (64..127)

    short8 wf[6][2];
    #pragma unroll
    for (int ks = 0; ks < 6; ++ks) {
        wf[ks][0] = *(const short8*)(wt2 + ((ks*4+q)*128 + cf)*8);
        wf[ks][1] = *(const short8*)(wt2 + ((ks*4+q)*128 + cc)*8);
    }
    float bs0 = bias[cf], bs1 = bias[cc];
    float sc0=0.f, sh0=0.f, sc1=0.f, sh1=0.f;
    if (PASS2) { sc0=bn1ss[cf]; sh0=bn1ss[128+cf]; sc1=bn1ss[cc]; sh1=bn1ss[128+cc]; }

    // staging slot constants (3 slots/thread, 704 lane-loads/task)
    int kind[3], ldso[3], nrow[3]; long gco[3];
    #pragma unroll
    for (int s = 0; s < 3; ++s) {
        int i = tid + s*256;
        if (i < 384)      { kind[s]=0; int row=i>>3, c=i&7; nrow[s]=row; ldso[s]=row*72+c*8; gco[s]=c*8; }
        else if (i < 672) { kind[s]=1; int j=i-384; int row=j/6, c=j%6; nrow[s]=0; ldso[s]=3456+row*56+c*8; gco[s]=row*48+c*8; }
        else if (i < 704) { kind[s]=2; int j=i-672; int a=j>>3, c=j&7; nrow[s]=0; ldso[s]=6144+a*72+c*8; gco[s]=a*64+c*8; }
        else              { kind[s]=3; nrow[s]=0; ldso[s]=0; gco[s]=0; }
    }
    // constant LDS read offsets (per thread)
    int art[3], nvo[3], evo[3], svo[3];
    #pragma unroll
    for (int rt = 0; rt < 3; ++rt) {
        int r = rt*16 + l15;
        art[rt] = r/12;
        nvo[rt] = r*72 + q*8;
        evo[rt] = 3456 + r*56 + q*8;
        svo[rt] = 6144 + art[rt]*72 + q*8;
    }

    float s_acc[2]={0.f,0.f}, s2_acc[2]={0.f,0.f};
    float st2s = 0.f, st2q = 0.f;
    const short8 zf = {0,0,0,0,0,0,0,0};
    float* pb = pbuf + wave*(12*17);
    const int bt = blockIdx.x;

    // ---- pipeline prologue: stage task 0, prefetch idx(task 1) ----
    int nid[3];
    short8 hold[3];
    #pragma unroll
    for (int s = 0; s < 3; ++s)
        if (kind[s]==0) nid[s] = nbr_idx[bt*48 + nrow[s]];
    #pragma unroll
    for (int s = 0; s < 3; ++s) {
        if (kind[s]==0)      hold[s] = *(const short8*)(abf + (unsigned)nid[s]*64u + gco[s]);
        else if (kind[s]==1) hold[s] = *(const short8*)(nbf + (long)bt*2304 + gco[s]);
        else if (kind[s]==2) hold[s] = *(const short8*)(abf + (unsigned)bt*256u + gco[s]);
    }
    #pragma unroll
    for (int s = 0; s < 3; ++s)
        if (kind[s]==0) nid[s] = nbr_idx[(bt+CGRID)*48 + nrow[s]];
    #pragma unroll
    for (int s = 0; s < 3; ++s)
        if (kind[s] < 3) *(short8*)(&stg[0][0] + ldso[s]) = hold[s];
    __syncthreads();

    #pragma unroll 2
    for (int k = 0; k < 8; ++k) {
        int b = bt + k*CGRID;
        // ---- issue next task's loads (overlap with compute below) ----
        if (k < 7) {
            int bn = b + CGRID;
            #pragma unroll
            for (int s = 0; s < 3; ++s) {
                if (kind[s]==0)      hold[s] = *(const short8*)(abf + (unsigned)nid[s]*64u + gco[s]);
                else if (kind[s]==1) hold[s] = *(const short8*)(nbf + (long)bn*2304 + gco[s]);
                else if (kind[s]==2) hold[s] = *(const short8*)(abf + (unsigned)bn*256u + gco[s]);
            }
            if (k < 6) {
                #pragma unroll
                for (int s = 0; s < 3; ++s)
                    if (kind[s]==0) nid[s] = nbr_idx[(bn+CGRID)*48 + nrow[s]];
            }
        }

        // ---- compute current task from LDS buffer k&1 ----
        const short* sb = &stg[k & 1][0];
        floatx4 acc[3][2];
        #pragma unroll
        for (int rt=0; rt<3; ++rt) {
            acc[rt][0] = (floatx4){bs0,bs0,bs0,bs0};
            acc[rt][1] = (floatx4){bs1,bs1,bs1,bs1};
        }
        #pragma unroll
        for (int rt = 0; rt < 3; ++rt) {
            short8 sv0 = *(const short8*)(sb + svo[rt]);
            short8 sv1 = *(const short8*)(sb + svo[rt] + 32);
            short8 nv0 = *(const short8*)(sb + nvo[rt]);
            short8 nv1 = *(const short8*)(sb + nvo[rt] + 32);
            short8 ev0 = *(const short8*)(sb + evo[rt]);
            short8 ev1 = (q < 2) ? *(const short8*)(sb + evo[rt] + 32) : zf;
            #pragma unroll
            for (int ct = 0; ct < 2; ++ct) {
                acc[rt][ct] = __builtin_amdgcn_mfma_f32_16x16x32_bf16(sv0, wf[0][ct], acc[rt][ct], 0,0,0);
                acc[rt][ct] = __builtin_amdgcn_mfma_f32_16x16x32_bf16(sv1, wf[1][ct], acc[rt][ct], 0,0,0);
                acc[rt][ct] = __builtin_amdgcn_mfma_f32_16x16x32_bf16(nv0, wf[2][ct], acc[rt][ct], 0,0,0);
                acc[rt][ct] = __builtin_amdgcn_mfma_f32_16x16x32_bf16(nv1, wf[3][ct], acc[rt][ct], 0,0,0);
                acc[rt][ct] = __builtin_amdgcn_mfma_f32_16x16x32_bf16(ev0, wf[4][ct], acc[rt][ct], 0,0,0);
                acc[rt][ct] = __builtin_amdgcn_mfma_f32_16x16x32_bf16(ev1, wf[5][ct], acc[rt][ct], 0,0,0);
            }
        }

        if (!PASS2) {
            #pragma unroll
            for (int ct=0; ct<2; ++ct)
                #pragma unroll
                for (int rt=0; rt<3; ++rt)
                    #pragma unroll
                    for (int r=0; r<4; ++r) {
                        float v = acc[rt][ct][r];
                        s_acc[ct] += v; s2_acc[ct] += v*v;
                    }
        } else {
            // 4-row partials: group g = rt*4+q holds rows g*4..g*4+3 (atom = g/3)
            #pragma unroll
            for (int rt=0; rt<3; ++rt) {
                float part = 0.f;
                #pragma unroll
                for (int r=0; r<4; ++r) {
                    float f = acc[rt][0][r]*sc0 + sh0;
                    float g = acc[rt][1][r]*sc1 + sh1;
                    part += sigmoidf_(f) * softplusf_(g);
                }
                pb[(rt*4+q)*17 + l15] = part;
            }
            // wave-private LDS: lgkmcnt ordering suffices, no barrier
            int a = lane >> 4, c16 = lane & 15;
            float s = pb[(3*a+0)*17 + c16] + pb[(3*a+1)*17 + c16] + pb[(3*a+2)*17 + c16];
            nsum[(b*4 + a)*AF + wave*16 + c16] = s;
            st2s += s; st2q += s*s;
        }

        // ---- commit next task's staging to the other buffer ----
        if (k < 7) {
            short* db = &stg[(k + 1) & 1][0];
            #pragma unroll
            for (int s = 0; s < 3; ++s)
                if (kind[s] < 3) *(short8*)(db + ldso[s]) = hold[s];
        }
        __syncthreads();
    }

    if (!PASS2) {
        #pragma unroll
        for (int ct=0; ct<2; ++ct) {
            float s = s_acc[ct], s2 = s2_acc[ct];
            s  += __shfl_xor(s, 16);  s  += __shfl_xor(s, 32);
            s2 += __shfl_xor(s2, 16); s2 += __shfl_xor(s2, 32);
            if (q == 0) {
                int c = ct ? cc : cf;
                atomicAdd(&stats1[c], s);
                atomicAdd(&stats1[128 + c], s2);
            }
        }
    } else {
        st2s += __shfl_xor(st2s, 16); st2s += __shfl_xor(st2s, 32);
        st2q += __shfl_xor(st2q, 16); st2q += __shfl_xor(st2q, 32);
        if (q == 0) {
            atomicAdd(&stats2[cf], st2s);
            atomicAdd(&stats2[64 + cf], st2q);
        }
    }
}

__global__ void k_bn1fin(const float* __restrict__ stats1, const float* __restrict__ g,
                         const float* __restrict__ b, float* __restrict__ bn1ss)
{
    int c = threadIdx.x;
    float mean = stats1[c] * (1.f/NMROW);
    float var  = stats1[128+c] * (1.f/NMROW) - mean*mean;
    float scale = g[c] * rsqrtf(var + EPSBN);
    bn1ss[c] = scale;
    bn1ss[128+c] = b[c] - mean*scale;
}

__global__ void k_update(float* __restrict__ afea, short* __restrict__ abf,
                         const float* __restrict__ nsum,
                         const float* __restrict__ stats2,
                         const float* __restrict__ g2, const float* __restrict__ b2)
{
    int g = blockIdx.x*256 + threadIdx.x;   // 16384 blocks
    int c = g & 63;
    float mean = stats2[c] * (1.f/NATOM);
    float var  = stats2[64+c] * (1.f/NATOM) - mean*mean;
    float scale = g2[c]*rsqrtf(var + EPSBN);
    float shift = b2[c] - mean*scale;
    float ns = nsum[g]*scale + shift;
    float a = afea[g];
    float v = softplusf_(a + ns) + a;       // afea == identity invariant
    afea[g] = v; abf[g] = f2bf(v);
}

__global__ void k_pool(const float* __restrict__ afea, const int* __restrict__ cidx,
                       float* __restrict__ pool, float* __restrict__ cnt)
{
    int g = blockIdx.x*256 + threadIdx.x;   // 1024 blocks
    int c = g & 63; int chunk = g >> 6;     // 4096 chunks x 16 atoms
    float run = 0.f, rc = 0.f; int cur = -1;
    for (int i = 0; i < 16; ++i) {
        int a = chunk*16 + i;
        int cr = cidx[a];
        float v = afea[a*64 + c];
        if (cr != cur) {
            if (cur >= 0) { atomicAdd(&pool[cur*64+c], run); if (c==0) atomicAdd(&cnt[cur], rc); }
            run = 0.f; rc = 0.f; cur = cr;
        }
        run += v; rc += 1.f;
    }
    atomicAdd(&pool[cur*64+c], run); if (c==0) atomicAdd(&cnt[cur], rc);
}

__global__ void k_head(const float* __restrict__ pool, const float* __restrict__ cnt,
                       const float* __restrict__ fc1w, const float* __restrict__ fc1b,
                       const float* __restrict__ o1w, const float* __restrict__ o1b,
                       const float* __restrict__ o2w, const float* __restrict__ o2b,
                       float* __restrict__ dout)
{
    __shared__ float spv[64], crys[128], h1[64];
    int b = blockIdx.x, tid = threadIdx.x;
    if (tid < 64) {
        float ct = fmaxf(cnt[b], 1.f);
        spv[tid] = softplusf_(pool[b*64+tid] / ct);
    }
    __syncthreads();
    float a = fc1b[tid];
    for (int k = 0; k < 64; ++k) a += spv[k] * fc1w[k*128 + tid];
    float v = softplusf_(a);
    crys[tid] = v;
    dout[NCRYS + b*128 + tid] = v;
    __syncthreads();
    if (tid < 64) {
        float a2 = o1b[tid];
        for (int k = 0; k < 128; ++k) a2 += crys[k] * o1w[k*64 + tid];
        h1[tid] = softplusf_(a2) * o2w[tid];
    }
    __syncthreads();
    if (tid == 0) {
        float s = o2b[0];
        for (int j = 0; j < 64; ++j) s += h1[j];
        dout[b] = s;
    }
}

extern "C" void kernel_launch(void* const* d_in, const int* in_sizes, int n_in,
                              void* d_out, int out_size, void* d_ws, size_t ws_size,
                              hipStream_t stream)
{
    const float* atom_fea = (const float*)d_in[0];
    const float* nbr_fea  = (const float*)d_in[1];
    const int*   nbr_idx  = (const int*)d_in[2];
    const int*   cidx     = (const int*)d_in[3];
    const float* emb_w    = (const float*)d_in[4];
    const float* emb_b    = (const float*)d_in[5];
    const float* cfw      = (const float*)d_in[6];
    const float* cfb      = (const float*)d_in[7];
    const float* bn1g     = (const float*)d_in[8];
    const float* bn1b     = (const float*)d_in[9];
    const float* bn2g     = (const float*)d_in[10];
    const float* bn2b     = (const float*)d_in[11];
    const float* fc1w     = (const float*)d_in[12];
    const float* fc1b     = (const float*)d_in[13];
    const float* o1w      = (const float*)d_in[14];
    const float* o1b      = (const float*)d_in[15];
    const float* o2w      = (const float*)d_in[16];
    const float* o2b      = (const float*)d_in[17];

    float* ws    = (float*)d_ws;
    float* afea  = ws;                         // [0, 4194304)
    float* nsum  = ws + 4194304;               // [4194304, 8388608)
    short* abf   = (short*)(ws + 8388608);     // 4194304 bf16
    short* nbf   = (short*)(ws + 10485760);    // NMROW*48 bf16
    short* wt2   = (short*)(ws + 29360128);    // 24576 bf16
    float* stats = ws + 29372416;              // 3 layers x 640
    float* pool  = ws + 29374336;              // 1024*64
    float* cnt   = ws + 29439872;              // 1024

    hipMemsetAsync(stats, 0, (1920 + 65536 + 1024)*sizeof(float), stream);

    k_prep_nbr<<<(NMROW*NBP)/256, 256, 0, stream>>>(nbr_fea, nbf);
    k_embed<<<2048, 256, 0, stream>>>(atom_fea, emb_w, emb_b, afea, abf);

    for (int L = 0; L < 3; ++L) {
        float* st1 = stats + L*640;
        float* ss  = st1 + 256;
        float* st2 = st1 + 512;
        k_prep_w<<<96, 256, 0, stream>>>(cfw + L*169*128, wt2);
        k_conv<0><<<CGRID, 256, 0, stream>>>(abf, nbf, nbr_idx, wt2, cfb + L*128, st1, nullptr, nullptr, nullptr);
        k_bn1fin<<<1, 128, 0, stream>>>(st1, bn1g + L*128, bn1b + L*128, ss);
        k_conv<1><<<CGRID, 256, 0, stream>>>(abf, nbf, nbr_idx, wt2, cfb + L*128, nullptr, ss, nsum, st2);
        k_update<<<16384, 256, 0, stream>>>(afea, abf, nsum, st2, bn2g + L*64, bn2b + L*64);
    }
    k_pool<<<1024, 256, 0, stream>>>(afea, cidx, pool, cnt);
    k_head<<<NCRYS, 128, 0, stream>>>(pool, cnt, fc1w, fc1b, o1w, o1b, o2w, o2b, (float*)d_out);
}

// Round 7
// 821.610 us; speedup vs baseline: 5.4098x; 1.0341x over previous
//
#include <hip/hip_runtime.h>

#define NATOM 65536
#define MNBR 12
#define NMROW (NATOM*MNBR)      // 786432
#define ORIG 92
#define NBRF 41
#define AF 64
#define HF 128
#define NCRYS 1024
#define EPSBN 1e-5f
#define NBP 48                  // padded edge width (bf16)
#define CGRID 2048
#define NTASK 16384             // 48-row tasks; 8 per block exactly

typedef __attribute__((ext_vector_type(8))) short short8;
typedef __attribute__((ext_vector_type(4))) float floatx4;

__device__ __forceinline__ float softplusf_(float x){
    return fmaxf(x,0.f) + __logf(1.f + __expf(-fabsf(x)));
}
__device__ __forceinline__ float sigmoidf_(float x){
    return __builtin_amdgcn_rcpf(1.f + __expf(-x));
}
__device__ __forceinline__ short f2bf(float x){
    unsigned u = __float_as_uint(x);
    u += 0x7fffu + ((u >> 16) & 1u);   // RNE
    return (short)(u >> 16);
}
__device__ __forceinline__ unsigned packbf(float f, float g){
    return (unsigned)(unsigned short)f2bf(f) | ((unsigned)(unsigned short)f2bf(g) << 16);
}

// ---------------- embedding: afea = atom_fea @ emb_w + emb_b ----------------
__global__ void k_embed(const float* __restrict__ atom_fea, const float* __restrict__ emb_w,
                        const float* __restrict__ emb_b, float* __restrict__ afea,
                        short* __restrict__ abf)
{
    __shared__ float wl[ORIG*AF];
    __shared__ float bl[AF];
    __shared__ float rows[4*ORIG];
    int tid = threadIdx.x;
    for (int i = tid; i < ORIG*AF; i += 256) wl[i] = emb_w[i];
    if (tid < AF) bl[tid] = emb_b[tid];
    __syncthreads();
    for (int t = blockIdx.x; t < NATOM/4; t += gridDim.x) {
        for (int i = tid; i < 4*ORIG; i += 256) rows[i] = atom_fea[t*4*ORIG + i];
        __syncthreads();
        int r = tid >> 6, c = tid & 63;
        float acc = bl[c];
        const float* rp = &rows[r*ORIG];
        #pragma unroll 4
        for (int k = 0; k < ORIG; ++k) acc += rp[k] * wl[k*AF + c];
        int n = t*4 + r;
        afea[n*AF + c] = acc;
        abf[n*AF + c] = f2bf(acc);
        __syncthreads();
    }
}

// ------------- one-time: nbr_fea fp32 [NM][41] -> bf16 padded [NM][48] -------------
// thread = (row, 8-chunk); short8 stores, coalesced 32B loads
__global__ void k_prep_nbr(const float* __restrict__ nbr_fea, short* __restrict__ nbf)
{
    int g = blockIdx.x*256 + threadIdx.x;   // NMROW*6 threads
    int row = g / 6, c = g % 6;
    const float* src = nbr_fea + (long)row*NBRF + c*8;
    short8 v = {0,0,0,0,0,0,0,0};
    if (c < 5) {
        #pragma unroll
        for (int j = 0; j < 8; ++j) v[j] = f2bf(src[j]);
    } else {
        v[0] = f2bf(src[0]);                // k=40 only
    }
    *(short8*)(nbf + (long)g*8) = v;
}

// ------------- per-layer: W fp32 [169][128] -> bf16 fragments [ks][q][c][j] -------------
__global__ void k_prep_w(const float* __restrict__ W, short* __restrict__ wt2)
{
    int g = blockIdx.x*256 + threadIdx.x;   // 24576 threads
    int j = g & 7, c = (g >> 3) & 127, q = (g >> 10) & 3, ks = g >> 12;
    int k = ks*32 + q*8 + j;
    wt2[g] = (k < 169) ? f2bf(W[k*128 + c]) : (short)0;
}

// ---------------- conv GEMM: gated = [self|nbr|edge] @ W + b ----------------
// Task = 48 rows (4 atoms) x 128 ch; block's 4 waves share rows, wave owns 16
// paired channels (filt cf = wave*16+l15, core cf+64). Double-buffered LDS
// staging, software-pipelined (idx prefetched 2 ahead). 8 tasks/block.
// MODE 0: stats1 only (fallback pass1). MODE 1: BN1+gate+m-sum (fallback pass2).
// MODE 2: stats1 + packed bf16 gated pairs -> gpair (single-GEMM path).
template<int MODE>
__global__ __launch_bounds__(256, 3)
void k_conv(const short* __restrict__ abf, const short* __restrict__ nbf,
            const int* __restrict__ nbr_idx, const short* __restrict__ wt2,
            const float* __restrict__ bias,
            float* __restrict__ stats1, const float* __restrict__ bn1ss,
            float* __restrict__ nsum, float* __restrict__ stats2,
            unsigned* __restrict__ gpair)
{
    __shared__ __align__(16) short stg[2][6432];
    __shared__ float pbuf[(MODE==1) ? 4*12*17 : 4];

    int tid = threadIdx.x;
    int lane = tid & 63, wave = tid >> 6;
    int l15 = lane & 15, q = lane >> 4;
    int cf = wave*16 + l15;
    int cc = 64 + cf;

    short8 wf[6][2];
    #pragma unroll
    for (int ks = 0; ks < 6; ++ks) {
        wf[ks][0] = *(const short8*)(wt2 + ((ks*4+q)*128 + cf)*8);
        wf[ks][1] = *(const short8*)(wt2 + ((ks*4+q)*128 + cc)*8);
    }
    float bs0 = bias[cf], bs1 = bias[cc];
    float sc0=0.f, sh0=0.f, sc1=0.f, sh1=0.f;
    if (MODE==1) { sc0=bn1ss[cf]; sh0=bn1ss[128+cf]; sc1=bn1ss[cc]; sh1=bn1ss[128+cc]; }

    int kind[3], ldso[3], nrow[3]; long gco[3];
    #pragma unroll
    for (int s = 0; s < 3; ++s) {
        int i = tid + s*256;
        if (i < 384)      { kind[s]=0; int row=i>>3, c=i&7; nrow[s]=row; ldso[s]=row*72+c*8; gco[s]=c*8; }
        else if (i < 672) { kind[s]=1; int j=i-384; int row=j/6, c=j%6; nrow[s]=0; ldso[s]=3456+row*56+c*8; gco[s]=row*48+c*8; }
        else if (i < 704) { kind[s]=2; int j=i-672; int a=j>>3, c=j&7; nrow[s]=0; ldso[s]=6144+a*72+c*8; gco[s]=a*64+c*8; }
        else              { kind[s]=3; nrow[s]=0; ldso[s]=0; gco[s]=0; }
    }
    int art[3], nvo[3], evo[3], svo[3];
    #pragma unroll
    for (int rt = 0; rt < 3; ++rt) {
        int r = rt*16 + l15;
        art[rt] = r/12;
        nvo[rt] = r*72 + q*8;
        evo[rt] = 3456 + r*56 + q*8;
        svo[rt] = 6144 + art[rt]*72 + q*8;
    }

    float s_acc[2]={0.f,0.f}, s2_acc[2]={0.f,0.f};
    float st2s = 0.f, st2q = 0.f;
    const short8 zf = {0,0,0,0,0,0,0,0};
    float* pb = pbuf + ((MODE==1) ? wave*(12*17) : 0);
    const int bt = blockIdx.x;

    int nid[3];
    short8 hold[3];
    #pragma unroll
    for (int s = 0; s < 3; ++s)
        if (kind[s]==0) nid[s] = nbr_idx[bt*48 + nrow[s]];
    #pragma unroll
    for (int s = 0; s < 3; ++s) {
        if (kind[s]==0)      hold[s] = *(const short8*)(abf + (unsigned)nid[s]*64u + gco[s]);
        else if (kind[s]==1) hold[s] = *(const short8*)(nbf + (long)bt*2304 + gco[s]);
        else if (kind[s]==2) hold[s] = *(const short8*)(abf + (unsigned)bt*256u + gco[s]);
    }
    #pragma unroll
    for (int s = 0; s < 3; ++s)
        if (kind[s]==0) nid[s] = nbr_idx[(bt+CGRID)*48 + nrow[s]];
    #pragma unroll
    for (int s = 0; s < 3; ++s)
        if (kind[s] < 3) *(short8*)(&stg[0][0] + ldso[s]) = hold[s];
    __syncthreads();

    #pragma unroll 2
    for (int k = 0; k < 8; ++k) {
        int b = bt + k*CGRID;
        if (k < 7) {
            int bn = b + CGRID;
            #pragma unroll
            for (int s = 0; s < 3; ++s) {
                if (kind[s]==0)      hold[s] = *(const short8*)(abf + (unsigned)nid[s]*64u + gco[s]);
                else if (kind[s]==1) hold[s] = *(const short8*)(nbf + (long)bn*2304 + gco[s]);
                else if (kind[s]==2) hold[s] = *(const short8*)(abf + (unsigned)bn*256u + gco[s]);
            }
            if (k < 6) {
                #pragma unroll
                for (int s = 0; s < 3; ++s)
                    if (kind[s]==0) nid[s] = nbr_idx[(bn+CGRID)*48 + nrow[s]];
            }
        }

        const short* sb = &stg[k & 1][0];
        floatx4 acc[3][2];
        #pragma unroll
        for (int rt=0; rt<3; ++rt) {
            acc[rt][0] = (floatx4){bs0,bs0,bs0,bs0};
            acc[rt][1] = (floatx4){bs1,bs1,bs1,bs1};
        }
        #pragma unroll
        for (int rt = 0; rt < 3; ++rt) {
            short8 sv0 = *(const short8*)(sb + svo[rt]);
            short8 sv1 = *(const short8*)(sb + svo[rt] + 32);
            short8 nv0 = *(const short8*)(sb + nvo[rt]);
            short8 nv1 = *(const short8*)(sb + nvo[rt] + 32);
            short8 ev0 = *(const short8*)(sb + evo[rt]);
            short8 ev1 = (q < 2) ? *(const short8*)(sb + evo[rt] + 32) : zf;
            #pragma unroll
            for (int ct = 0; ct < 2; ++ct) {
                acc[rt][ct] = __builtin_amdgcn_mfma_f32_16x16x32_bf16(sv0, wf[0][ct], acc[rt][ct], 0,0,0);
                acc[rt][ct] = __builtin_amdgcn_mfma_f32_16x16x32_bf16(sv1, wf[1][ct], acc[rt][ct], 0,0,0);
                acc[rt][ct] = __builtin_amdgcn_mfma_f32_16x16x32_bf16(nv0, wf[2][ct], acc[rt][ct], 0,0,0);
                acc[rt][ct] = __builtin_amdgcn_mfma_f32_16x16x32_bf16(nv1, wf[3][ct], acc[rt][ct], 0,0,0);
                acc[rt][ct] = __builtin_amdgcn_mfma_f32_16x16x32_bf16(ev0, wf[4][ct], acc[rt][ct], 0,0,0);
                acc[rt][ct] = __builtin_amdgcn_mfma_f32_16x16x32_bf16(ev1, wf[5][ct], acc[rt][ct], 0,0,0);
            }
        }

        if (MODE != 1) {
            #pragma unroll
            for (int ct=0; ct<2; ++ct)
                #pragma unroll
                for (int rt=0; rt<3; ++rt)
                    #pragma unroll
                    for (int r=0; r<4; ++r) {
                        float v = acc[rt][ct][r];
                        s_acc[ct] += v; s2_acc[ct] += v*v;
                    }
        }
        if (MODE == 2) {
            // gated pair store: row = b*48 + rt*16 + q*4 + r, pair pc = wave*16+l15
            #pragma unroll
            for (int rt=0; rt<3; ++rt) {
                unsigned base = (unsigned)(b*48 + rt*16 + q*4)*64u + (unsigned)(wave*16 + l15);
                #pragma unroll
                for (int r=0; r<4; ++r)
                    gpair[base + (unsigned)r*64u] = packbf(acc[rt][0][r], acc[rt][1][r]);
            }
        }
        if (MODE == 1) {
            #pragma unroll
            for (int rt=0; rt<3; ++rt) {
                float part = 0.f;
                #pragma unroll
                for (int r=0; r<4; ++r) {
                    float f = acc[rt][0][r]*sc0 + sh0;
                    float g = acc[rt][1][r]*sc1 + sh1;
                    part += sigmoidf_(f) * softplusf_(g);
                }
                pb[(rt*4+q)*17 + l15] = part;
            }
            int a = lane >> 4, c16 = lane & 15;
            float s = pb[(3*a+0)*17 + c16] + pb[(3*a+1)*17 + c16] + pb[(3*a+2)*17 + c16];
            nsum[(b*4 + a)*AF + wave*16 + c16] = s;
            st2s += s; st2q += s*s;
        }

        if (k < 7) {
            short* db = &stg[(k + 1) & 1][0];
            #pragma unroll
            for (int s = 0; s < 3; ++s)
                if (kind[s] < 3) *(short8*)(db + ldso[s]) = hold[s];
        }
        __syncthreads();
    }

    if (MODE != 1) {
        #pragma unroll
        for (int ct=0; ct<2; ++ct) {
            float s = s_acc[ct], s2 = s2_acc[ct];
            s  += __shfl_xor(s, 16);  s  += __shfl_xor(s, 32);
            s2 += __shfl_xor(s2, 16); s2 += __shfl_xor(s2, 32);
            if (q == 0) {
                int c = ct ? cc : cf;
                atomicAdd(&stats1[c], s);
                atomicAdd(&stats1[128 + c], s2);
            }
        }
    } else {
        st2s += __shfl_xor(st2s, 16); st2s += __shfl_xor(st2s, 32);
        st2q += __shfl_xor(st2q, 16); st2q += __shfl_xor(st2q, 32);
        if (q == 0) {
            atomicAdd(&stats2[cf], st2s);
            atomicAdd(&stats2[64 + cf], st2q);
        }
    }
}

// -------- elementwise pass 2 (big-ws path): BN1 + sigmoid*softplus + m-sum --------
// block = 64 atoms (16 iters x 4 waves); thread = (wave-> atom slot, lane -> pair ch)
__global__ __launch_bounds__(256, 4)
void k_gate(const unsigned* __restrict__ gpair, const float* __restrict__ bn1ss,
            float* __restrict__ nsum, float* __restrict__ stats2)
{
    __shared__ float red[2][4][64];
    int tid = threadIdx.x;
    int lane = tid & 63, wave = tid >> 6;
    float scf = bn1ss[lane],    shf = bn1ss[128+lane];
    float scc = bn1ss[64+lane], shc = bn1ss[192+lane];
    float st2s = 0.f, st2q = 0.f;
    int a0 = blockIdx.x*64 + wave;
    for (int j = 0; j < 16; ++j) {
        int atom = a0 + j*4;
        const unsigned* gp = gpair + (unsigned)atom*12u*64u + lane;
        unsigned u[12];
        #pragma unroll
        for (int i = 0; i < 12; ++i) u[i] = gp[i*64];
        float s = 0.f;
        #pragma unroll
        for (int i = 0; i < 12; ++i) {
            float f = __uint_as_float(u[i] << 16);
            float g = __uint_as_float(u[i] & 0xffff0000u);
            f = f*scf + shf;
            g = g*scc + shc;
            s += sigmoidf_(f) * softplusf_(g);
        }
        nsum[atom*AF + lane] = s;
        st2s += s; st2q += s*s;
    }
    red[0][wave][lane] = st2s;
    red[1][wave][lane] = st2q;
    __syncthreads();
    if (tid < 64) {
        float s  = red[0][0][tid] + red[0][1][tid] + red[0][2][tid] + red[0][3][tid];
        float s2 = red[1][0][tid] + red[1][1][tid] + red[1][2][tid] + red[1][3][tid];
        atomicAdd(&stats2[tid], s);
        atomicAdd(&stats2[64 + tid], s2);
    }
}

__global__ void k_bn1fin(const float* __restrict__ stats1, const float* __restrict__ g,
                         const float* __restrict__ b, float* __restrict__ bn1ss)
{
    int c = threadIdx.x;
    float mean = stats1[c] * (1.f/NMROW);
    float var  = stats1[128+c] * (1.f/NMROW) - mean*mean;
    float scale = g[c] * rsqrtf(var + EPSBN);
    bn1ss[c] = scale;
    bn1ss[128+c] = b[c] - mean*scale;
}

__global__ void k_update(float* __restrict__ afea, short* __restrict__ abf,
                         const float* __restrict__ nsum,
                         const float* __restrict__ stats2,
                         const float* __restrict__ g2, const float* __restrict__ b2)
{
    int g = blockIdx.x*256 + threadIdx.x;   // 16384 blocks
    int c = g & 63;
    float mean = stats2[c] * (1.f/NATOM);
    float var  = stats2[64+c] * (1.f/NATOM) - mean*mean;
    float scale = g2[c]*rsqrtf(var + EPSBN);
    float shift = b2[c] - mean*scale;
    float ns = nsum[g]*scale + shift;
    float a = afea[g];
    float v = softplusf_(a + ns) + a;       // afea == identity invariant
    afea[g] = v; abf[g] = f2bf(v);
}

__global__ void k_pool(const float* __restrict__ afea, const int* __restrict__ cidx,
                       float* __restrict__ pool, float* __restrict__ cnt)
{
    int g = blockIdx.x*256 + threadIdx.x;   // 1024 blocks
    int c = g & 63; int chunk = g >> 6;     // 4096 chunks x 16 atoms
    float run = 0.f, rc = 0.f; int cur = -1;
    for (int i = 0; i < 16; ++i) {
        int a = chunk*16 + i;
        int cr = cidx[a];
        float v = afea[a*64 + c];
        if (cr != cur) {
            if (cur >= 0) { atomicAdd(&pool[cur*64+c], run); if (c==0) atomicAdd(&cnt[cur], rc); }
            run = 0.f; rc = 0.f; cur = cr;
        }
        run += v; rc += 1.f;
    }
    atomicAdd(&pool[cur*64+c], run); if (c==0) atomicAdd(&cnt[cur], rc);
}

__global__ void k_head(const float* __restrict__ pool, const float* __restrict__ cnt,
                       const float* __restrict__ fc1w, const float* __restrict__ fc1b,
                       const float* __restrict__ o1w, const float* __restrict__ o1b,
                       const float* __restrict__ o2w, const float* __restrict__ o2b,
                       float* __restrict__ dout)
{
    __shared__ float spv[64], crys[128], h1[64];
    int b = blockIdx.x, tid = threadIdx.x;
    if (tid < 64) {
        float ct = fmaxf(cnt[b], 1.f);
        spv[tid] = softplusf_(pool[b*64+tid] / ct);
    }
    __syncthreads();
    float a = fc1b[tid];
    for (int k = 0; k < 64; ++k) a += spv[k] * fc1w[k*128 + tid];
    float v = softplusf_(a);
    crys[tid] = v;
    dout[NCRYS + b*128 + tid] = v;
    __syncthreads();
    if (tid < 64) {
        float a2 = o1b[tid];
        for (int k = 0; k < 128; ++k) a2 += crys[k] * o1w[k*64 + tid];
        h1[tid] = softplusf_(a2) * o2w[tid];
    }
    __syncthreads();
    if (tid == 0) {
        float s = o2b[0];
        for (int j = 0; j < 64; ++j) s += h1[j];
        dout[b] = s;
    }
}

extern "C" void kernel_launch(void* const* d_in, const int* in_sizes, int n_in,
                              void* d_out, int out_size, void* d_ws, size_t ws_size,
                              hipStream_t stream)
{
    const float* atom_fea = (const float*)d_in[0];
    const float* nbr_fea  = (const float*)d_in[1];
    const int*   nbr_idx  = (const int*)d_in[2];
    const int*   cidx     = (const int*)d_in[3];
    const float* emb_w    = (const float*)d_in[4];
    const float* emb_b    = (const float*)d_in[5];
    const float* cfw      = (const float*)d_in[6];
    const float* cfb      = (const float*)d_in[7];
    const float* bn1g     = (const float*)d_in[8];
    const float* bn1b     = (const float*)d_in[9];
    const float* bn2g     = (const float*)d_in[10];
    const float* bn2b     = (const float*)d_in[11];
    const float* fc1w     = (const float*)d_in[12];
    const float* fc1b     = (const float*)d_in[13];
    const float* o1w      = (const float*)d_in[14];
    const float* o1b      = (const float*)d_in[15];
    const float* o2w      = (const float*)d_in[16];
    const float* o2b      = (const float*)d_in[17];

    float* ws    = (float*)d_ws;
    float* afea  = ws;                         // 16 MB
    float* nsum  = ws + 4194304;               // 16 MB
    short* abf   = (short*)(ws + 8388608);     // 8 MB
    short* nbf   = (short*)(ws + 10485760);    // 75.5 MB
    short* wt2   = (short*)(ws + 29360128);    // 48 KB
    float* stats = ws + 29372416;              // 3 x 640
    float* pool  = ws + 29374336;              // 256 KB
    float* cnt   = ws + 29439872;              // 4 KB
    unsigned* gpair = (unsigned*)(ws + 29440896); // 201 MB (big-ws path only)

    bool big = ws_size >= (size_t)(29440896 + 50331648) * 4;

    hipMemsetAsync(stats, 0, (1920 + 65536 + 1024)*sizeof(float), stream);

    k_prep_nbr<<<(NMROW*6)/256, 256, 0, stream>>>(nbr_fea, nbf);
    k_embed<<<2048, 256, 0, stream>>>(atom_fea, emb_w, emb_b, afea, abf);

    for (int L = 0; L < 3; ++L) {
        float* st1 = stats + L*640;
        float* ss  = st1 + 256;
        float* st2 = st1 + 512;
        k_prep_w<<<96, 256, 0, stream>>>(cfw + L*169*128, wt2);
        if (big) {
            k_conv<2><<<CGRID, 256, 0, stream>>>(abf, nbf, nbr_idx, wt2, cfb + L*128,
                                                 st1, nullptr, nullptr, nullptr, gpair);
            k_bn1fin<<<1, 128, 0, stream>>>(st1, bn1g + L*128, bn1b + L*128, ss);
            k_gate<<<NATOM/64, 256, 0, stream>>>(gpair, ss, nsum, st2);
        } else {
            k_conv<0><<<CGRID, 256, 0, stream>>>(abf, nbf, nbr_idx, wt2, cfb + L*128,
                                                 st1, nullptr, nullptr, nullptr, nullptr);
            k_bn1fin<<<1, 128, 0, stream>>>(st1, bn1g + L*128, bn1b + L*128, ss);
            k_conv<1><<<CGRID, 256, 0, stream>>>(abf, nbf, nbr_idx, wt2, cfb + L*128,
                                                 nullptr, ss, nsum, st2, nullptr);
        }
        k_update<<<16384, 256, 0, stream>>>(afea, abf, nsum, st2, bn2g + L*64, bn2b + L*64);
    }
    k_pool<<<1024, 256, 0, stream>>>(afea, cidx, pool, cnt);
    k_head<<<NCRYS, 128, 0, stream>>>(pool, cnt, fc1w, fc1b, o1w, o1b, o2w, o2b, (float*)d_out);
}